// Round 4
// baseline (410.928 us; speedup 1.0000x reference)
//
#include <hip/hip_runtime.h>

#define NEG_SLOPE 0.2f

__device__ __forceinline__ float lrelu(float x) {
    return fmaxf(x, 0.0f) + NEG_SLOPE * fminf(x, 0.0f);
}

// monotonic float<->uint key for atomicMax on floats (any sign)
__device__ __forceinline__ unsigned fkey(float f) {
    unsigned u = __float_as_uint(f);
    return (u & 0x80000000u) ? ~u : (u | 0x80000000u);
}
__device__ __forceinline__ float funkey(unsigned k) {
    return __uint_as_float((k & 0x80000000u) ? (k & 0x7fffffffu) : ~k);
}

// ---------------- CSR construction ----------------

__global__ void hist_kernel(const int* __restrict__ dst, int* __restrict__ cnt, int E) {
    int e = blockIdx.x * 256 + threadIdx.x;
    if (e < E) atomicAdd(&cnt[dst[e]], 1);
}

__global__ __launch_bounds__(256) void scan_reduce(const int* __restrict__ cnt,
                                                   int* __restrict__ bsum, int n) {
    __shared__ int sm[256];
    int base = blockIdx.x * 1024 + threadIdx.x * 4;
    int s = 0;
#pragma unroll
    for (int j = 0; j < 4; ++j) {
        int i = base + j;
        if (i < n) s += cnt[i];
    }
    sm[threadIdx.x] = s;
    __syncthreads();
#pragma unroll
    for (int off = 128; off >= 1; off >>= 1) {
        if (threadIdx.x < off) sm[threadIdx.x] += sm[threadIdx.x + off];
        __syncthreads();
    }
    if (threadIdx.x == 0) bsum[blockIdx.x] = sm[0];
}

__global__ __launch_bounds__(64) void scan_bsum(int* __restrict__ bsum, int nb) {
    int v = (threadIdx.x < (unsigned)nb) ? bsum[threadIdx.x] : 0;
    int x = v;
#pragma unroll
    for (int off = 1; off < 64; off <<= 1) {
        int y = __shfl_up(x, off);
        if ((int)threadIdx.x >= off) x += y;
    }
    if (threadIdx.x < (unsigned)nb) bsum[threadIdx.x] = x - v;  // exclusive
}

__global__ __launch_bounds__(256) void scan_write(const int* __restrict__ cnt,
                                                  const int* __restrict__ bsum,
                                                  int* __restrict__ rp, int n) {
    __shared__ int sm[256];
    int base = blockIdx.x * 1024 + threadIdx.x * 4;
    int v[4];
    int s = 0;
#pragma unroll
    for (int j = 0; j < 4; ++j) {
        int i = base + j;
        v[j] = (i < n) ? cnt[i] : 0;
        s += v[j];
    }
    sm[threadIdx.x] = s;
    __syncthreads();
#pragma unroll
    for (int off = 1; off < 256; off <<= 1) {
        int y = (threadIdx.x >= off) ? sm[threadIdx.x - off] : 0;
        __syncthreads();
        sm[threadIdx.x] += y;
        __syncthreads();
    }
    int run = sm[threadIdx.x] - s + bsum[blockIdx.x];
#pragma unroll
    for (int j = 0; j < 4; ++j) {
        int i = base + j;
        if (i < n) {
            rp[i] = run;
            run += v[j];
            if (i == n - 1) rp[n] = run;
        }
    }
}

__global__ void scatter_kernel(const int* __restrict__ src, const int* __restrict__ dst,
                               const int* __restrict__ rp, int* __restrict__ fill,
                               int* __restrict__ csr, int E) {
    int e = blockIdx.x * 256 + threadIdx.x;
    if (e < E) {
        int d = dst[e];
        int pos = rp[d] + atomicAdd(&fill[d], 1);
        csr[pos] = src[e];
    }
}

// ---------------- global per-head max of alS ----------------

template <int H>
__global__ __launch_bounds__(256) void gmax_kernel(const float* __restrict__ a,
                                                   unsigned* __restrict__ gm, int total) {
    __shared__ unsigned sm[256];
    unsigned loc = 0;
    int stride = 256 * gridDim.x;
    for (int i = blockIdx.x * 256 + threadIdx.x; i < total; i += stride)
        loc = max(loc, fkey(a[i]));
    sm[threadIdx.x] = loc;
    __syncthreads();
    for (int off = 128; off >= H; off >>= 1) {
        if (threadIdx.x < off) sm[threadIdx.x] = max(sm[threadIdx.x], sm[threadIdx.x + off]);
        __syncthreads();
    }
    if (threadIdx.x < H) atomicMax(&gm[threadIdx.x], sm[threadIdx.x]);
}

// ---------------- GEMM: C[M,NC(+pad)] = A[M,128] @ B[128,NC] ----------------

template <int NC, int OSTR>
__global__ __launch_bounds__(256) void gemm_k128(const float* __restrict__ A,
                                                 const float* __restrict__ B,
                                                 float* __restrict__ C, int M) {
    constexpr int BSTR = (NC + 3) & ~3;
    __shared__ float As[128][36];
    __shared__ float Bs[32][BSTR];

    float acc[8][8];
#pragma unroll
    for (int i = 0; i < 8; ++i)
#pragma unroll
        for (int j = 0; j < 8; ++j) acc[i][j] = 0.0f;

    const int trow = threadIdx.x >> 4;
    const int tcol = threadIdx.x & 15;
    const int rbase = blockIdx.x * 128;

    for (int kt = 0; kt < 4; ++kt) {
#pragma unroll
        for (int q = 0; q < 4; ++q) {
            int v = threadIdx.x + q * 256;
            int r = v >> 3, k4 = v & 7;
            float4 val = make_float4(0.f, 0.f, 0.f, 0.f);
            int row = rbase + r;
            if (row < M) val = *(const float4*)&A[row * 128 + kt * 32 + k4 * 4];
            *(float4*)&As[r][k4 * 4] = val;
        }
        for (int i = threadIdx.x; i < 32 * BSTR; i += 256) {
            int k = i / BSTR, c = i % BSTR;
            Bs[k][c] = (c < NC) ? B[(kt * 32 + k) * NC + c] : 0.0f;
        }
        __syncthreads();

#pragma unroll
        for (int k = 0; k < 32; k += 4) {
            float a_[8][4];
#pragma unroll
            for (int i = 0; i < 8; ++i) {
                float4 t = *(const float4*)&As[trow * 8 + i][k];
                a_[i][0] = t.x; a_[i][1] = t.y; a_[i][2] = t.z; a_[i][3] = t.w;
            }
#pragma unroll
            for (int kk = 0; kk < 4; ++kk) {
                float4 bx = *(const float4*)&Bs[k + kk][tcol * 8];
                float4 by = *(const float4*)&Bs[k + kk][tcol * 8 + 4];
#pragma unroll
                for (int i = 0; i < 8; ++i) {
                    float a = a_[i][kk];
                    acc[i][0] = fmaf(a, bx.x, acc[i][0]);
                    acc[i][1] = fmaf(a, bx.y, acc[i][1]);
                    acc[i][2] = fmaf(a, bx.z, acc[i][2]);
                    acc[i][3] = fmaf(a, bx.w, acc[i][3]);
                    acc[i][4] = fmaf(a, by.x, acc[i][4]);
                    acc[i][5] = fmaf(a, by.y, acc[i][5]);
                    acc[i][6] = fmaf(a, by.z, acc[i][6]);
                    acc[i][7] = fmaf(a, by.w, acc[i][7]);
                }
            }
        }
        __syncthreads();
    }

#pragma unroll
    for (int i = 0; i < 8; ++i) {
        int row = rbase + trow * 8 + i;
        if (row >= M) continue;
        if constexpr (NC == OSTR) {
            float4 v0 = make_float4(acc[i][0], acc[i][1], acc[i][2], acc[i][3]);
            float4 v1 = make_float4(acc[i][4], acc[i][5], acc[i][6], acc[i][7]);
            *(float4*)&C[row * OSTR + tcol * 8] = v0;
            *(float4*)&C[row * OSTR + tcol * 8 + 4] = v1;
        } else {
#pragma unroll
            for (int j = 0; j < 8; ++j) {
                int c = tcol * 8 + j;
                if (c < NC) C[row * OSTR + c] = acc[i][j];
            }
        }
    }
}

// ---------------- attention logit dot products ----------------

__global__ void al1_kernel(const float* __restrict__ h1, const float* __restrict__ as,
                           const float* __restrict__ ad, float* __restrict__ alS,
                           float* __restrict__ alD, int N) {
    int g = blockIdx.x * 256 + threadIdx.x;
    if (g >= N * 8) return;
    int r = g >> 3, h = g & 7;
    const float* hp = h1 + r * 128 + h * 16;
    const float* sp = as + h * 16;
    const float* dp = ad + h * 16;
    float s = 0.f, d = 0.f;
#pragma unroll
    for (int q = 0; q < 16; ++q) {
        float v = hp[q];
        s = fmaf(v, sp[q], s);
        d = fmaf(v, dp[q], d);
    }
    alS[g] = s;
    alD[g] = d;
}

// h3 row stride = HSTR (padded)
__global__ __launch_bounds__(256) void al2_kernel(const float* __restrict__ h3,
                                                  const float* __restrict__ as,
                                                  const float* __restrict__ ad,
                                                  float* __restrict__ alS,
                                                  float* __restrict__ alD, int N, int NC,
                                                  int HSTR) {
    int lane = threadIdx.x & 63;
    int r = blockIdx.x * 4 + (threadIdx.x >> 6);
    if (r >= N) return;
    float s = 0.f, d = 0.f;
    for (int c = lane; c < NC; c += 64) {
        float v = h3[r * HSTR + c];
        s = fmaf(v, as[c], s);
        d = fmaf(v, ad[c], d);
    }
#pragma unroll
    for (int off = 32; off; off >>= 1) {
        s += __shfl_down(s, off);
        d += __shfl_down(d, off);
    }
    if (lane == 0) { alS[r] = s; alD[r] = d; }
}

// ---------------- layer-1 aggregation: LDS-staged edge weights ----------------
// 128 threads per dst node. Chunk = 16 edges; weight phase: thread (j,hh)=(tid>>3,tid&7)
// computes one exp; fma phase: thread tid = (h,dim) gathers features.

__global__ __launch_bounds__(128) void agg1_kernel(
    const float* __restrict__ h1, const float* __restrict__ alS,
    const float* __restrict__ alD, const float* __restrict__ b1,
    const int* __restrict__ rp, const int* __restrict__ csr,
    const unsigned* __restrict__ gm, float* __restrict__ h2, int N) {
    __shared__ float adv[8], mh[8];
    __shared__ int ssm[16];
    __shared__ float wsm[16][8];

    int t = blockIdx.x;
    int tid = threadIdx.x;
    int h = tid >> 4;

    if (tid < 8) {
        float a = alD[t * 8 + tid];
        adv[tid] = a;
        mh[tid] = lrelu(funkey(gm[tid]) + a);
    }
    __syncthreads();

    int e0 = rp[t], e1 = rp[t + 1];

    float ex = __expf(lrelu(alS[t * 8 + h] + adv[h]) - mh[h]);  // self loop
    float dsum = ex;
    float facc = ex * h1[t * 128 + tid];

    for (int c0 = e0; c0 < e1; c0 += 16) {
        int k = min(16, e1 - c0);
        // weight phase: 128 threads = 16 edges x 8 heads
        int j = tid >> 3, hh = tid & 7;
        if (j < k) {
            int s = csr[c0 + j];
            if (hh == 0) ssm[j] = s;
            wsm[j][hh] = __expf(lrelu(alS[s * 8 + hh] + adv[hh]) - mh[hh]);
        }
        __syncthreads();
        // fma phase
#pragma unroll 4
        for (int q = 0; q < k; ++q) {
            float w = wsm[q][h];
            dsum += w;
            facc = fmaf(w, h1[ssm[q] * 128 + tid], facc);
        }
        __syncthreads();
    }
    float o = facc / dsum + b1[tid];
    h2[t * 128 + tid] = fmaxf(o, 0.0f);
}

// ---------------- layer-2 aggregation: LDS-staged edge weights ----------------
// 128 threads per dst node; chunk = 128 edges; h3 row stride HSTR (padded to 128).

__global__ __launch_bounds__(128) void agg2_kernel(
    const float* __restrict__ h3, const float* __restrict__ alS,
    const float* __restrict__ alD, const float* __restrict__ b2,
    const int* __restrict__ rp, const int* __restrict__ csr,
    const unsigned* __restrict__ gm, float* __restrict__ out, int N, int NC, int HSTR) {
    __shared__ int ssm[128];
    __shared__ float wsm[128];

    int t = blockIdx.x;
    int tid = threadIdx.x;
    float adT = alD[t];
    float m = lrelu(funkey(gm[0]) + adT);
    int e0 = rp[t], e1 = rp[t + 1];

    float ex = __expf(lrelu(alS[t] + adT) - m);
    float dsum = ex;
    float facc = (tid < NC) ? ex * h3[t * HSTR + tid] : 0.0f;

    for (int c0 = e0; c0 < e1; c0 += 128) {
        int k = min(128, e1 - c0);
        if (tid < k) {
            int s = csr[c0 + tid];
            ssm[tid] = s;
            wsm[tid] = __expf(lrelu(alS[s] + adT) - m);
        }
        __syncthreads();
#pragma unroll 4
        for (int q = 0; q < k; ++q) {
            float w = wsm[q];
            dsum += w;
            if (tid < NC) facc = fmaf(w, h3[ssm[q] * HSTR + tid], facc);
        }
        __syncthreads();
    }
    if (tid < NC) out[t * NC + tid] = facc / dsum + b2[tid];
}

// ---------------- host launcher ----------------

extern "C" void kernel_launch(void* const* d_in, const int* in_sizes, int n_in,
                              void* d_out, int out_size, void* d_ws, size_t ws_size,
                              hipStream_t stream) {
    const float* x   = (const float*)d_in[0];
    const int*   ei  = (const int*)d_in[1];
    const float* W1  = (const float*)d_in[2];
    const float* aS1 = (const float*)d_in[3];
    const float* aD1 = (const float*)d_in[4];
    const float* b1  = (const float*)d_in[5];
    const float* W2  = (const float*)d_in[6];
    const float* aS2 = (const float*)d_in[7];
    const float* aD2 = (const float*)d_in[8];
    const float* b2  = (const float*)d_in[9];
    float* out = (float*)d_out;

    const int N = in_sizes[0] / 128;   // 50000
    const int E = in_sizes[1] / 2;     // 800000
    const int NC2 = 121;
    const int HSTR = 128;              // padded h3 row stride

    size_t off = 0;
    auto alloc = [&](size_t bytes) {
        size_t o = off;
        off = (off + bytes + 255) & ~(size_t)255;
        return o;
    };
    char* ws = (char*)d_ws;
    int*      cnt  = (int*)(ws + alloc((size_t)N * 4));
    int*      fill = (int*)(ws + alloc((size_t)N * 4));
    int*      rp   = (int*)(ws + alloc((size_t)(N + 1) * 4));
    int*      csr  = (int*)(ws + alloc((size_t)E * 4));
    int*      bsum = (int*)(ws + alloc(64 * 4));
    float*    alS1 = (float*)(ws + alloc((size_t)N * 8 * 4));
    float*    alD1 = (float*)(ws + alloc((size_t)N * 8 * 4));
    float*    alS2 = (float*)(ws + alloc((size_t)N * 4));
    float*    alD2 = (float*)(ws + alloc((size_t)N * 4));
    unsigned* gm1  = (unsigned*)(ws + alloc(8 * 4));
    unsigned* gm2  = (unsigned*)(ws + alloc(4));
    float*    h1   = (float*)(ws + alloc((size_t)N * 128 * 4));
    float*    h2   = (float*)(ws + alloc((size_t)N * 128 * 4));
    float*    h3   = h1;  // h1 dead after agg1; same footprint (N*128)
    if (ws_size < off) return;

    const int* src = ei;
    const int* dst = ei + E;

    hipMemsetAsync(cnt, 0, (size_t)N * 4, stream);
    hipMemsetAsync(fill, 0, (size_t)N * 4, stream);
    hipMemsetAsync(gm1, 0, 8 * 4, stream);
    hipMemsetAsync(gm2, 0, 4, stream);

    int eb = (E + 255) / 256;
    int nb = (N + 1023) / 1024;  // <= 64
    hist_kernel<<<eb, 256, 0, stream>>>(dst, cnt, E);
    scan_reduce<<<nb, 256, 0, stream>>>(cnt, bsum, N);
    scan_bsum<<<1, 64, 0, stream>>>(bsum, nb);
    scan_write<<<nb, 256, 0, stream>>>(cnt, bsum, rp, N);
    scatter_kernel<<<eb, 256, 0, stream>>>(src, dst, rp, fill, csr, E);

    int gb = (N + 127) / 128;
    gemm_k128<128, 128><<<gb, 256, 0, stream>>>(x, W1, h1, N);
    al1_kernel<<<(N * 8 + 255) / 256, 256, 0, stream>>>(h1, aS1, aD1, alS1, alD1, N);
    gmax_kernel<8><<<128, 256, 0, stream>>>(alS1, gm1, N * 8);
    agg1_kernel<<<N, 128, 0, stream>>>(h1, alS1, alD1, b1, rp, csr, gm1, h2, N);

    gemm_k128<121, 128><<<gb, 256, 0, stream>>>(h2, W2, h3, N);
    al2_kernel<<<(N + 3) / 4, 256, 0, stream>>>(h3, aS2, aD2, alS2, alD2, N, NC2, HSTR);
    gmax_kernel<1><<<128, 256, 0, stream>>>(alS2, gm2, N);
    agg2_kernel<<<N, 128, 0, stream>>>(h3, alS2, alD2, b2, rp, csr, gm2, out, N, NC2, HSTR);
}

// Round 5
// 390.415 us; speedup vs baseline: 1.0525x; 1.0525x over previous
//
#include <hip/hip_runtime.h>
#include <hip/hip_fp16.h>

#define NEG_SLOPE 0.2f

__device__ __forceinline__ float lrelu(float x) {
    return fmaxf(x, 0.0f) + NEG_SLOPE * fminf(x, 0.0f);
}

// monotonic float<->uint key for atomicMax on floats (any sign)
__device__ __forceinline__ unsigned fkey(float f) {
    unsigned u = __float_as_uint(f);
    return (u & 0x80000000u) ? ~u : (u | 0x80000000u);
}
__device__ __forceinline__ float funkey(unsigned k) {
    return __uint_as_float((k & 0x80000000u) ? (k & 0x7fffffffu) : ~k);
}

// ---------------- CSR construction ----------------

__global__ void hist_kernel(const int* __restrict__ dst, int* __restrict__ cnt, int E) {
    int e = blockIdx.x * 256 + threadIdx.x;
    if (e < E) atomicAdd(&cnt[dst[e]], 1);
}

__global__ __launch_bounds__(256) void scan_reduce(const int* __restrict__ cnt,
                                                   int* __restrict__ bsum, int n) {
    __shared__ int sm[256];
    int base = blockIdx.x * 1024 + threadIdx.x * 4;
    int s = 0;
#pragma unroll
    for (int j = 0; j < 4; ++j) {
        int i = base + j;
        if (i < n) s += cnt[i];
    }
    sm[threadIdx.x] = s;
    __syncthreads();
#pragma unroll
    for (int off = 128; off >= 1; off >>= 1) {
        if (threadIdx.x < off) sm[threadIdx.x] += sm[threadIdx.x + off];
        __syncthreads();
    }
    if (threadIdx.x == 0) bsum[blockIdx.x] = sm[0];
}

__global__ __launch_bounds__(64) void scan_bsum(int* __restrict__ bsum, int nb) {
    int v = (threadIdx.x < (unsigned)nb) ? bsum[threadIdx.x] : 0;
    int x = v;
#pragma unroll
    for (int off = 1; off < 64; off <<= 1) {
        int y = __shfl_up(x, off);
        if ((int)threadIdx.x >= off) x += y;
    }
    if (threadIdx.x < (unsigned)nb) bsum[threadIdx.x] = x - v;  // exclusive
}

__global__ __launch_bounds__(256) void scan_write(const int* __restrict__ cnt,
                                                  const int* __restrict__ bsum,
                                                  int* __restrict__ rp, int n) {
    __shared__ int sm[256];
    int base = blockIdx.x * 1024 + threadIdx.x * 4;
    int v[4];
    int s = 0;
#pragma unroll
    for (int j = 0; j < 4; ++j) {
        int i = base + j;
        v[j] = (i < n) ? cnt[i] : 0;
        s += v[j];
    }
    sm[threadIdx.x] = s;
    __syncthreads();
#pragma unroll
    for (int off = 1; off < 256; off <<= 1) {
        int y = (threadIdx.x >= off) ? sm[threadIdx.x - off] : 0;
        __syncthreads();
        sm[threadIdx.x] += y;
        __syncthreads();
    }
    int run = sm[threadIdx.x] - s + bsum[blockIdx.x];
#pragma unroll
    for (int j = 0; j < 4; ++j) {
        int i = base + j;
        if (i < n) {
            rp[i] = run;
            run += v[j];
            if (i == n - 1) rp[n] = run;
        }
    }
}

// scatter src AND dst per CSR slot
__global__ void scatter_kernel(const int* __restrict__ src, const int* __restrict__ dst,
                               const int* __restrict__ rp, int* __restrict__ fill,
                               int* __restrict__ csr, int* __restrict__ dstc, int E) {
    int e = blockIdx.x * 256 + threadIdx.x;
    if (e < E) {
        int d = dst[e];
        int pos = rp[d] + atomicAdd(&fill[d], 1);
        csr[pos] = src[e];
        dstc[pos] = d;
    }
}

// ---------------- global per-head max of alS ----------------

template <int H>
__global__ __launch_bounds__(256) void gmax_kernel(const float* __restrict__ a,
                                                   unsigned* __restrict__ gm, int total) {
    __shared__ unsigned sm[256];
    unsigned loc = 0;
    int stride = 256 * gridDim.x;
    for (int i = blockIdx.x * 256 + threadIdx.x; i < total; i += stride)
        loc = max(loc, fkey(a[i]));
    sm[threadIdx.x] = loc;
    __syncthreads();
    for (int off = 128; off >= H; off >>= 1) {
        if (threadIdx.x < off) sm[threadIdx.x] = max(sm[threadIdx.x], sm[threadIdx.x + off]);
        __syncthreads();
    }
    if (threadIdx.x < H) atomicMax(&gm[threadIdx.x], sm[threadIdx.x]);
}

// ---------------- GEMM: C[M,OSTR(half)] = A[M,128] @ B[128,NC] ----------------

template <int NC, int OSTR>
__global__ __launch_bounds__(256) void gemm_k128_h(const float* __restrict__ A,
                                                   const float* __restrict__ B,
                                                   __half* __restrict__ C, int M) {
    constexpr int BSTR = (NC + 3) & ~3;
    __shared__ float As[128][36];
    __shared__ float Bs[32][BSTR];

    float acc[8][8];
#pragma unroll
    for (int i = 0; i < 8; ++i)
#pragma unroll
        for (int j = 0; j < 8; ++j) acc[i][j] = 0.0f;

    const int trow = threadIdx.x >> 4;
    const int tcol = threadIdx.x & 15;
    const int rbase = blockIdx.x * 128;

    for (int kt = 0; kt < 4; ++kt) {
#pragma unroll
        for (int q = 0; q < 4; ++q) {
            int v = threadIdx.x + q * 256;
            int r = v >> 3, k4 = v & 7;
            float4 val = make_float4(0.f, 0.f, 0.f, 0.f);
            int row = rbase + r;
            if (row < M) val = *(const float4*)&A[row * 128 + kt * 32 + k4 * 4];
            *(float4*)&As[r][k4 * 4] = val;
        }
        for (int i = threadIdx.x; i < 32 * BSTR; i += 256) {
            int k = i / BSTR, c = i % BSTR;
            Bs[k][c] = (c < NC) ? B[(kt * 32 + k) * NC + c] : 0.0f;
        }
        __syncthreads();

#pragma unroll
        for (int k = 0; k < 32; k += 4) {
            float a_[8][4];
#pragma unroll
            for (int i = 0; i < 8; ++i) {
                float4 t = *(const float4*)&As[trow * 8 + i][k];
                a_[i][0] = t.x; a_[i][1] = t.y; a_[i][2] = t.z; a_[i][3] = t.w;
            }
#pragma unroll
            for (int kk = 0; kk < 4; ++kk) {
                float4 bx = *(const float4*)&Bs[k + kk][tcol * 8];
                float4 by = *(const float4*)&Bs[k + kk][tcol * 8 + 4];
#pragma unroll
                for (int i = 0; i < 8; ++i) {
                    float a = a_[i][kk];
                    acc[i][0] = fmaf(a, bx.x, acc[i][0]);
                    acc[i][1] = fmaf(a, bx.y, acc[i][1]);
                    acc[i][2] = fmaf(a, bx.z, acc[i][2]);
                    acc[i][3] = fmaf(a, bx.w, acc[i][3]);
                    acc[i][4] = fmaf(a, by.x, acc[i][4]);
                    acc[i][5] = fmaf(a, by.y, acc[i][5]);
                    acc[i][6] = fmaf(a, by.z, acc[i][6]);
                    acc[i][7] = fmaf(a, by.w, acc[i][7]);
                }
            }
        }
        __syncthreads();
    }

#pragma unroll
    for (int i = 0; i < 8; ++i) {
        int row = rbase + trow * 8 + i;
        if (row >= M) continue;
        if constexpr (NC == OSTR) {
            union { float4 f4; __half2 h2v[4]; } u;
#pragma unroll
            for (int p = 0; p < 4; ++p) {
                __half2 hv;
                hv.x = __float2half(acc[i][2 * p]);
                hv.y = __float2half(acc[i][2 * p + 1]);
                u.h2v[p] = hv;
            }
            *(float4*)&C[(size_t)row * OSTR + tcol * 8] = u.f4;
        } else {
#pragma unroll
            for (int j = 0; j < 8; ++j) {
                int c = tcol * 8 + j;
                C[(size_t)row * OSTR + c] = __float2half(c < NC ? acc[i][j] : 0.0f);
            }
        }
    }
}

// ---------------- attention logit dot products ----------------

__global__ void al1_kernel(const __half* __restrict__ h1h, const float* __restrict__ as,
                           const float* __restrict__ ad, float* __restrict__ alS,
                           float* __restrict__ alD, int N) {
    int g = blockIdx.x * 256 + threadIdx.x;
    if (g >= N * 8) return;
    int r = g >> 3, h = g & 7;
    const __half2* hp = (const __half2*)(h1h + (size_t)r * 128 + h * 16);
    const float* sp = as + h * 16;
    const float* dp = ad + h * 16;
    float s = 0.f, d = 0.f;
#pragma unroll
    for (int q = 0; q < 8; ++q) {
        float2 v = __half22float2(hp[q]);
        s = fmaf(v.x, sp[2 * q], s);
        d = fmaf(v.x, dp[2 * q], d);
        s = fmaf(v.y, sp[2 * q + 1], s);
        d = fmaf(v.y, dp[2 * q + 1], d);
    }
    alS[g] = s;
    alD[g] = d;
}

// h3h row stride = 128 halfs
__global__ __launch_bounds__(256) void al2_kernel(const __half* __restrict__ h3h,
                                                  const float* __restrict__ as,
                                                  const float* __restrict__ ad,
                                                  float* __restrict__ alS,
                                                  float* __restrict__ alD, int N, int NC) {
    int lane = threadIdx.x & 63;
    int r = blockIdx.x * 4 + (threadIdx.x >> 6);
    if (r >= N) return;
    float s = 0.f, d = 0.f;
    for (int c = lane; c < NC; c += 64) {
        float v = __half2float(h3h[(size_t)r * 128 + c]);
        s = fmaf(v, as[c], s);
        d = fmaf(v, ad[c], d);
    }
#pragma unroll
    for (int off = 32; off; off >>= 1) {
        s += __shfl_down(s, off);
        d += __shfl_down(d, off);
    }
    if (lane == 0) { alS[r] = s; alD[r] = d; }
}

// ---------------- layer-2 edge weights (CSR order, one exp per edge) ----------------

__global__ void w2_kernel(const int* __restrict__ csr, const int* __restrict__ dstc,
                          const float* __restrict__ alS, const float* __restrict__ alD,
                          const unsigned* __restrict__ gm, float* __restrict__ w2v, int E) {
    int e = blockIdx.x * 256 + threadIdx.x;
    if (e >= E) return;
    int s = csr[e], t = dstc[e];
    float adT = alD[t];
    w2v[e] = __expf(lrelu(alS[s] + adT) - lrelu(funkey(gm[0]) + adT));
}

// ---------------- layer-1 aggregation: shuffle-shared weights, barrier-free ----------
// 128 threads per dst node; tid = h*16+d. Per 16-edge chunk each lane computes ONE
// (edge j, head hh) exp; fma loop broadcasts weight/src via __shfl within the wave.

__global__ __launch_bounds__(128) void agg1_kernel(
    const __half* __restrict__ h1h, const float* __restrict__ alS,
    const float* __restrict__ alD, const float* __restrict__ b1,
    const int* __restrict__ rp, const int* __restrict__ csr,
    const unsigned* __restrict__ gm, float* __restrict__ h2, int N) {
    int t = blockIdx.x;
    int tid = threadIdx.x;
    int h = tid >> 4;               // this thread's head (0..7)
    int lane = tid & 63;
    int j = lane & 15;              // edge slot this lane computes
    int hh = ((tid >> 6) << 2) + (lane >> 4);  // head this lane computes (wave*4 + grp)

    float adh = alD[t * 8 + h];
    float mh = lrelu(funkey(gm[h]) + adh);
    float adhh = alD[t * 8 + hh];
    float mhh = lrelu(funkey(gm[hh]) + adhh);

    int e0 = rp[t], e1 = rp[t + 1];

    float ex = __expf(lrelu(alS[t * 8 + h] + adh) - mh);  // self loop
    float dsum = ex;
    float facc = ex * __half2float(h1h[(size_t)t * 128 + tid]);

    for (int c0 = e0; c0 < e1; c0 += 16) {
        int k = min(16, e1 - c0);
        int sj = t;
        float wj = 0.f;
        if (j < k) {
            sj = csr[c0 + j];
            wj = __expf(lrelu(alS[sj * 8 + hh] + adhh) - mhh);
        }
        int base = lane & 48;
#pragma unroll 4
        for (int q = 0; q < k; ++q) {
            float wq = __shfl(wj, base | q);
            int sq = __shfl(sj, q);
            dsum += wq;
            facc = fmaf(wq, __half2float(h1h[(size_t)sq * 128 + tid]), facc);
        }
    }
    float o = facc / dsum + b1[tid];
    h2[(size_t)t * 128 + tid] = fmaxf(o, 0.0f);
}

// ---------------- layer-2 aggregation: precomputed weights, barrier-free ----------

__global__ __launch_bounds__(128) void agg2_kernel(
    const __half* __restrict__ h3h, const float* __restrict__ alS,
    const float* __restrict__ alD, const float* __restrict__ b2,
    const int* __restrict__ rp, const int* __restrict__ csr,
    const float* __restrict__ w2v, const unsigned* __restrict__ gm,
    float* __restrict__ out, int N, int NC) {
    int t = blockIdx.x;
    int tid = threadIdx.x;
    float adT = alD[t];
    float m = lrelu(funkey(gm[0]) + adT);
    int e0 = rp[t], e1 = rp[t + 1];

    float ex = __expf(lrelu(alS[t] + adT) - m);
    float dsum = ex;
    float facc = ex * __half2float(h3h[(size_t)t * 128 + tid]);  // pad cols are 0

    int e = e0;
    for (; e + 4 <= e1; e += 4) {
        int s0 = csr[e], s1 = csr[e + 1], s2 = csr[e + 2], s3 = csr[e + 3];
        float w0 = w2v[e], w1 = w2v[e + 1], w2 = w2v[e + 2], w3 = w2v[e + 3];
        float f0 = __half2float(h3h[(size_t)s0 * 128 + tid]);
        float f1 = __half2float(h3h[(size_t)s1 * 128 + tid]);
        float f2 = __half2float(h3h[(size_t)s2 * 128 + tid]);
        float f3 = __half2float(h3h[(size_t)s3 * 128 + tid]);
        dsum += (w0 + w1) + (w2 + w3);
        facc = fmaf(w0, f0, facc);
        facc = fmaf(w1, f1, facc);
        facc = fmaf(w2, f2, facc);
        facc = fmaf(w3, f3, facc);
    }
    for (; e < e1; ++e) {
        int s0 = csr[e];
        float w0 = w2v[e];
        dsum += w0;
        facc = fmaf(w0, __half2float(h3h[(size_t)s0 * 128 + tid]), facc);
    }
    if (tid < NC) out[(size_t)t * NC + tid] = facc / dsum + b2[tid];
}

// ---------------- host launcher ----------------

extern "C" void kernel_launch(void* const* d_in, const int* in_sizes, int n_in,
                              void* d_out, int out_size, void* d_ws, size_t ws_size,
                              hipStream_t stream) {
    const float* x   = (const float*)d_in[0];
    const int*   ei  = (const int*)d_in[1];
    const float* W1  = (const float*)d_in[2];
    const float* aS1 = (const float*)d_in[3];
    const float* aD1 = (const float*)d_in[4];
    const float* b1  = (const float*)d_in[5];
    const float* W2  = (const float*)d_in[6];
    const float* aS2 = (const float*)d_in[7];
    const float* aD2 = (const float*)d_in[8];
    const float* b2  = (const float*)d_in[9];
    float* out = (float*)d_out;

    const int N = in_sizes[0] / 128;   // 50000
    const int E = in_sizes[1] / 2;     // 800000
    const int NC2 = 121;

    size_t off = 0;
    auto alloc = [&](size_t bytes) {
        size_t o = off;
        off = (off + bytes + 255) & ~(size_t)255;
        return o;
    };
    char* ws = (char*)d_ws;
    int*      cnt  = (int*)(ws + alloc((size_t)N * 4));
    int*      fill = (int*)(ws + alloc((size_t)N * 4));
    int*      rp   = (int*)(ws + alloc((size_t)(N + 1) * 4));
    int*      csr  = (int*)(ws + alloc((size_t)E * 4));
    int*      dstc = (int*)(ws + alloc((size_t)E * 4));
    int*      bsum = (int*)(ws + alloc(64 * 4));
    float*    alS1 = (float*)(ws + alloc((size_t)N * 8 * 4));
    float*    alD1 = (float*)(ws + alloc((size_t)N * 8 * 4));
    float*    alS2 = (float*)(ws + alloc((size_t)N * 4));
    float*    alD2 = (float*)(ws + alloc((size_t)N * 4));
    unsigned* gm1  = (unsigned*)(ws + alloc(8 * 4));
    unsigned* gm2  = (unsigned*)(ws + alloc(4));
    float*    w2v  = (float*)(ws + alloc((size_t)E * 4));
    __half*   h1h  = (__half*)(ws + alloc((size_t)N * 128 * 2));
    float*    h2   = (float*)(ws + alloc((size_t)N * 128 * 4));
    __half*   h3h  = h1h;  // h1h dead after agg1; reuse (same footprint)
    if (ws_size < off) return;

    const int* src = ei;
    const int* dst = ei + E;

    hipMemsetAsync(cnt, 0, (size_t)N * 4, stream);
    hipMemsetAsync(fill, 0, (size_t)N * 4, stream);
    hipMemsetAsync(gm1, 0, 8 * 4, stream);
    hipMemsetAsync(gm2, 0, 4, stream);

    int eb = (E + 255) / 256;
    int nb = (N + 1023) / 1024;  // <= 64
    hist_kernel<<<eb, 256, 0, stream>>>(dst, cnt, E);
    scan_reduce<<<nb, 256, 0, stream>>>(cnt, bsum, N);
    scan_bsum<<<1, 64, 0, stream>>>(bsum, nb);
    scan_write<<<nb, 256, 0, stream>>>(cnt, bsum, rp, N);
    scatter_kernel<<<eb, 256, 0, stream>>>(src, dst, rp, fill, csr, dstc, E);

    int gb = (N + 127) / 128;
    gemm_k128_h<128, 128><<<gb, 256, 0, stream>>>(x, W1, h1h, N);
    al1_kernel<<<(N * 8 + 255) / 256, 256, 0, stream>>>(h1h, aS1, aD1, alS1, alD1, N);
    gmax_kernel<8><<<128, 256, 0, stream>>>(alS1, gm1, N * 8);
    agg1_kernel<<<N, 128, 0, stream>>>(h1h, alS1, alD1, b1, rp, csr, gm1, h2, N);

    gemm_k128_h<121, 128><<<gb, 256, 0, stream>>>(h2, W2, h3h, N);
    al2_kernel<<<(N + 3) / 4, 256, 0, stream>>>(h3h, aS2, aD2, alS2, alD2, N, NC2);
    gmax_kernel<1><<<128, 256, 0, stream>>>(alS2, gm2, N);
    w2_kernel<<<eb, 256, 0, stream>>>(csr, dstc, alS2, alD2, gm2, w2v, E);
    agg2_kernel<<<N, 128, 0, stream>>>(h3h, alS2, alD2, b2, rp, csr, w2v, gm2, out, N, NC2);
}

// Round 6
// 307.658 us; speedup vs baseline: 1.3357x; 1.2690x over previous
//
#include <hip/hip_runtime.h>
#include <hip/hip_fp16.h>

#define NEG_SLOPE 0.2f

__device__ __forceinline__ float lrelu(float x) {
    return fmaxf(x, 0.0f) + NEG_SLOPE * fminf(x, 0.0f);
}

// monotonic float<->uint key for atomicMax on floats (any sign)
__device__ __forceinline__ unsigned fkey(float f) {
    unsigned u = __float_as_uint(f);
    return (u & 0x80000000u) ? ~u : (u | 0x80000000u);
}
__device__ __forceinline__ float funkey(unsigned k) {
    return __uint_as_float((k & 0x80000000u) ? (k & 0x7fffffffu) : ~k);
}

// ---------------- CSR construction ----------------

__global__ void hist_kernel(const int* __restrict__ dst, int* __restrict__ cnt, int E) {
    int e = blockIdx.x * 256 + threadIdx.x;
    if (e < E) atomicAdd(&cnt[dst[e]], 1);
}

__global__ __launch_bounds__(256) void scan_reduce(const int* __restrict__ cnt,
                                                   int* __restrict__ bsum, int n) {
    __shared__ int sm[256];
    int base = blockIdx.x * 1024 + threadIdx.x * 4;
    int s = 0;
#pragma unroll
    for (int j = 0; j < 4; ++j) {
        int i = base + j;
        if (i < n) s += cnt[i];
    }
    sm[threadIdx.x] = s;
    __syncthreads();
#pragma unroll
    for (int off = 128; off >= 1; off >>= 1) {
        if (threadIdx.x < off) sm[threadIdx.x] += sm[threadIdx.x + off];
        __syncthreads();
    }
    if (threadIdx.x == 0) bsum[blockIdx.x] = sm[0];
}

__global__ __launch_bounds__(64) void scan_bsum(int* __restrict__ bsum, int nb) {
    int v = (threadIdx.x < (unsigned)nb) ? bsum[threadIdx.x] : 0;
    int x = v;
#pragma unroll
    for (int off = 1; off < 64; off <<= 1) {
        int y = __shfl_up(x, off);
        if ((int)threadIdx.x >= off) x += y;
    }
    if (threadIdx.x < (unsigned)nb) bsum[threadIdx.x] = x - v;  // exclusive
}

__global__ __launch_bounds__(256) void scan_write(const int* __restrict__ cnt,
                                                  const int* __restrict__ bsum,
                                                  int* __restrict__ rp, int n) {
    __shared__ int sm[256];
    int base = blockIdx.x * 1024 + threadIdx.x * 4;
    int v[4];
    int s = 0;
#pragma unroll
    for (int j = 0; j < 4; ++j) {
        int i = base + j;
        v[j] = (i < n) ? cnt[i] : 0;
        s += v[j];
    }
    sm[threadIdx.x] = s;
    __syncthreads();
#pragma unroll
    for (int off = 1; off < 256; off <<= 1) {
        int y = (threadIdx.x >= off) ? sm[threadIdx.x - off] : 0;
        __syncthreads();
        sm[threadIdx.x] += y;
        __syncthreads();
    }
    int run = sm[threadIdx.x] - s + bsum[blockIdx.x];
#pragma unroll
    for (int j = 0; j < 4; ++j) {
        int i = base + j;
        if (i < n) {
            rp[i] = run;
            run += v[j];
            if (i == n - 1) rp[n] = run;
        }
    }
}

__global__ void scatter_kernel(const int* __restrict__ src, const int* __restrict__ dst,
                               const int* __restrict__ rp, int* __restrict__ fill,
                               int* __restrict__ csr, int E) {
    int e = blockIdx.x * 256 + threadIdx.x;
    if (e < E) {
        int d = dst[e];
        int pos = rp[d] + atomicAdd(&fill[d], 1);
        csr[pos] = src[e];
    }
}

// ---------------- global per-head max of alS ----------------

template <int H>
__global__ __launch_bounds__(256) void gmax_kernel(const float* __restrict__ a,
                                                   unsigned* __restrict__ gm, int total) {
    __shared__ unsigned sm[256];
    unsigned loc = 0;
    int stride = 256 * gridDim.x;
    for (int i = blockIdx.x * 256 + threadIdx.x; i < total; i += stride)
        loc = max(loc, fkey(a[i]));
    sm[threadIdx.x] = loc;
    __syncthreads();
    for (int off = 128; off >= H; off >>= 1) {
        if (threadIdx.x < off) sm[threadIdx.x] = max(sm[threadIdx.x], sm[threadIdx.x + off]);
        __syncthreads();
    }
    if (threadIdx.x < H) atomicMax(&gm[threadIdx.x], sm[threadIdx.x]);
}

// ---------------- GEMM: C[M,OSTR(half)] = A[M,128] @ B[128,NC] ----------------

template <int NC, int OSTR>
__global__ __launch_bounds__(256) void gemm_k128_h(const float* __restrict__ A,
                                                   const float* __restrict__ B,
                                                   __half* __restrict__ C, int M) {
    constexpr int BSTR = (NC + 3) & ~3;
    __shared__ float As[128][36];
    __shared__ float Bs[32][BSTR];

    float acc[8][8];
#pragma unroll
    for (int i = 0; i < 8; ++i)
#pragma unroll
        for (int j = 0; j < 8; ++j) acc[i][j] = 0.0f;

    const int trow = threadIdx.x >> 4;
    const int tcol = threadIdx.x & 15;
    const int rbase = blockIdx.x * 128;

    for (int kt = 0; kt < 4; ++kt) {
#pragma unroll
        for (int q = 0; q < 4; ++q) {
            int v = threadIdx.x + q * 256;
            int r = v >> 3, k4 = v & 7;
            float4 val = make_float4(0.f, 0.f, 0.f, 0.f);
            int row = rbase + r;
            if (row < M) val = *(const float4*)&A[row * 128 + kt * 32 + k4 * 4];
            *(float4*)&As[r][k4 * 4] = val;
        }
        for (int i = threadIdx.x; i < 32 * BSTR; i += 256) {
            int k = i / BSTR, c = i % BSTR;
            Bs[k][c] = (c < NC) ? B[(kt * 32 + k) * NC + c] : 0.0f;
        }
        __syncthreads();

#pragma unroll
        for (int k = 0; k < 32; k += 4) {
            float a_[8][4];
#pragma unroll
            for (int i = 0; i < 8; ++i) {
                float4 t = *(const float4*)&As[trow * 8 + i][k];
                a_[i][0] = t.x; a_[i][1] = t.y; a_[i][2] = t.z; a_[i][3] = t.w;
            }
#pragma unroll
            for (int kk = 0; kk < 4; ++kk) {
                float4 bx = *(const float4*)&Bs[k + kk][tcol * 8];
                float4 by = *(const float4*)&Bs[k + kk][tcol * 8 + 4];
#pragma unroll
                for (int i = 0; i < 8; ++i) {
                    float a = a_[i][kk];
                    acc[i][0] = fmaf(a, bx.x, acc[i][0]);
                    acc[i][1] = fmaf(a, bx.y, acc[i][1]);
                    acc[i][2] = fmaf(a, bx.z, acc[i][2]);
                    acc[i][3] = fmaf(a, bx.w, acc[i][3]);
                    acc[i][4] = fmaf(a, by.x, acc[i][4]);
                    acc[i][5] = fmaf(a, by.y, acc[i][5]);
                    acc[i][6] = fmaf(a, by.z, acc[i][6]);
                    acc[i][7] = fmaf(a, by.w, acc[i][7]);
                }
            }
        }
        __syncthreads();
    }

#pragma unroll
    for (int i = 0; i < 8; ++i) {
        int row = rbase + trow * 8 + i;
        if (row >= M) continue;
        if constexpr (NC == OSTR) {
            union { float4 f4; __half2 h2v[4]; } u;
#pragma unroll
            for (int p = 0; p < 4; ++p) {
                __half2 hv;
                hv.x = __float2half(acc[i][2 * p]);
                hv.y = __float2half(acc[i][2 * p + 1]);
                u.h2v[p] = hv;
            }
            *(float4*)&C[(size_t)row * OSTR + tcol * 8] = u.f4;
        } else {
#pragma unroll
            for (int j = 0; j < 8; ++j) {
                int c = tcol * 8 + j;
                C[(size_t)row * OSTR + c] = __float2half(c < NC ? acc[i][j] : 0.0f);
            }
        }
    }
}

// ---------------- attention logit dot products ----------------

__global__ void al1_kernel(const __half* __restrict__ h1h, const float* __restrict__ as,
                           const float* __restrict__ ad, float* __restrict__ alS,
                           float* __restrict__ alD, int N) {
    int g = blockIdx.x * 256 + threadIdx.x;
    if (g >= N * 8) return;
    int r = g >> 3, h = g & 7;
    const __half2* hp = (const __half2*)(h1h + (size_t)r * 128 + h * 16);
    const float* sp = as + h * 16;
    const float* dp = ad + h * 16;
    float s = 0.f, d = 0.f;
#pragma unroll
    for (int q = 0; q < 8; ++q) {
        float2 v = __half22float2(hp[q]);
        s = fmaf(v.x, sp[2 * q], s);
        d = fmaf(v.x, dp[2 * q], d);
        s = fmaf(v.y, sp[2 * q + 1], s);
        d = fmaf(v.y, dp[2 * q + 1], d);
    }
    alS[g] = s;
    alD[g] = d;
}

// h3h row stride = 128 halfs
__global__ __launch_bounds__(256) void al2_kernel(const __half* __restrict__ h3h,
                                                  const float* __restrict__ as,
                                                  const float* __restrict__ ad,
                                                  float* __restrict__ alS,
                                                  float* __restrict__ alD, int N, int NC) {
    int lane = threadIdx.x & 63;
    int r = blockIdx.x * 4 + (threadIdx.x >> 6);
    if (r >= N) return;
    float s = 0.f, d = 0.f;
    for (int c = lane; c < NC; c += 64) {
        float v = __half2float(h3h[(size_t)r * 128 + c]);
        s = fmaf(v, as[c], s);
        d = fmaf(v, ad[c], d);
    }
#pragma unroll
    for (int off = 32; off; off >>= 1) {
        s += __shfl_down(s, off);
        d += __shfl_down(d, off);
    }
    if (lane == 0) { alS[r] = s; alD[r] = d; }
}

// ---------------- layer-1 aggregation: one wave per dst node, half2 lanes --------
// lane handles features 2*lane, 2*lane+1; head h = lane>>3. Weight computed inline
// per lane (8-way redundant within wave; cheap). Barrier-free, shuffle-free.

__global__ __launch_bounds__(256) void agg1_kernel(
    const __half* __restrict__ h1h, const float* __restrict__ alS,
    const float* __restrict__ alD, const float* __restrict__ b1,
    const int* __restrict__ rp, const int* __restrict__ csr,
    const unsigned* __restrict__ gm, float* __restrict__ h2, int N) {
    int t = blockIdx.x * 4 + (threadIdx.x >> 6);
    if (t >= N) return;
    int lane = threadIdx.x & 63;
    int h = lane >> 3;

    float adh = alD[t * 8 + h];
    float mh = lrelu(funkey(gm[h]) + adh);
    int e0 = rp[t], e1 = rp[t + 1];

    float ex = __expf(lrelu(alS[t * 8 + h] + adh) - mh);  // self loop
    float dsum = ex;
    float2 hs = __half22float2(*(const __half2*)(h1h + (size_t)t * 128 + 2 * lane));
    float fx = ex * hs.x, fy = ex * hs.y;

    int e = e0;
    for (; e + 4 <= e1; e += 4) {
        int s0 = csr[e], s1 = csr[e + 1], s2 = csr[e + 2], s3 = csr[e + 3];
        float w0 = __expf(lrelu(alS[s0 * 8 + h] + adh) - mh);
        float w1 = __expf(lrelu(alS[s1 * 8 + h] + adh) - mh);
        float w2 = __expf(lrelu(alS[s2 * 8 + h] + adh) - mh);
        float w3 = __expf(lrelu(alS[s3 * 8 + h] + adh) - mh);
        float2 f0 = __half22float2(*(const __half2*)(h1h + (size_t)s0 * 128 + 2 * lane));
        float2 f1 = __half22float2(*(const __half2*)(h1h + (size_t)s1 * 128 + 2 * lane));
        float2 f2 = __half22float2(*(const __half2*)(h1h + (size_t)s2 * 128 + 2 * lane));
        float2 f3 = __half22float2(*(const __half2*)(h1h + (size_t)s3 * 128 + 2 * lane));
        dsum += (w0 + w1) + (w2 + w3);
        fx = fmaf(w0, f0.x, fx); fy = fmaf(w0, f0.y, fy);
        fx = fmaf(w1, f1.x, fx); fy = fmaf(w1, f1.y, fy);
        fx = fmaf(w2, f2.x, fx); fy = fmaf(w2, f2.y, fy);
        fx = fmaf(w3, f3.x, fx); fy = fmaf(w3, f3.y, fy);
    }
    for (; e < e1; ++e) {
        int s0 = csr[e];
        float w0 = __expf(lrelu(alS[s0 * 8 + h] + adh) - mh);
        float2 f0 = __half22float2(*(const __half2*)(h1h + (size_t)s0 * 128 + 2 * lane));
        dsum += w0;
        fx = fmaf(w0, f0.x, fx); fy = fmaf(w0, f0.y, fy);
    }
    float inv = 1.0f / dsum;
    float2 bb = *(const float2*)(b1 + 2 * lane);
    float ox = fmaxf(fmaf(fx, inv, bb.x), 0.0f);
    float oy = fmaxf(fmaf(fy, inv, bb.y), 0.0f);
    *(float2*)(h2 + (size_t)t * 128 + 2 * lane) = make_float2(ox, oy);
}

// ---------------- layer-2 aggregation: one wave per dst node, half2 lanes --------

__global__ __launch_bounds__(256) void agg2_kernel(
    const __half* __restrict__ h3h, const float* __restrict__ alS,
    const float* __restrict__ alD, const float* __restrict__ b2,
    const int* __restrict__ rp, const int* __restrict__ csr,
    const unsigned* __restrict__ gm, float* __restrict__ out, int N, int NC) {
    int t = blockIdx.x * 4 + (threadIdx.x >> 6);
    if (t >= N) return;
    int lane = threadIdx.x & 63;

    float adT = alD[t];
    float m = lrelu(funkey(gm[0]) + adT);
    int e0 = rp[t], e1 = rp[t + 1];

    float ex = __expf(lrelu(alS[t] + adT) - m);
    float dsum = ex;
    float2 hs = __half22float2(*(const __half2*)(h3h + (size_t)t * 128 + 2 * lane));
    float fx = ex * hs.x, fy = ex * hs.y;  // pad cols are 0

    int e = e0;
    for (; e + 4 <= e1; e += 4) {
        int s0 = csr[e], s1 = csr[e + 1], s2 = csr[e + 2], s3 = csr[e + 3];
        float w0 = __expf(lrelu(alS[s0] + adT) - m);
        float w1 = __expf(lrelu(alS[s1] + adT) - m);
        float w2 = __expf(lrelu(alS[s2] + adT) - m);
        float w3 = __expf(lrelu(alS[s3] + adT) - m);
        float2 f0 = __half22float2(*(const __half2*)(h3h + (size_t)s0 * 128 + 2 * lane));
        float2 f1 = __half22float2(*(const __half2*)(h3h + (size_t)s1 * 128 + 2 * lane));
        float2 f2 = __half22float2(*(const __half2*)(h3h + (size_t)s2 * 128 + 2 * lane));
        float2 f3 = __half22float2(*(const __half2*)(h3h + (size_t)s3 * 128 + 2 * lane));
        dsum += (w0 + w1) + (w2 + w3);
        fx = fmaf(w0, f0.x, fx); fy = fmaf(w0, f0.y, fy);
        fx = fmaf(w1, f1.x, fx); fy = fmaf(w1, f1.y, fy);
        fx = fmaf(w2, f2.x, fx); fy = fmaf(w2, f2.y, fy);
        fx = fmaf(w3, f3.x, fx); fy = fmaf(w3, f3.y, fy);
    }
    for (; e < e1; ++e) {
        int s0 = csr[e];
        float w0 = __expf(lrelu(alS[s0] + adT) - m);
        float2 f0 = __half22float2(*(const __half2*)(h3h + (size_t)s0 * 128 + 2 * lane));
        dsum += w0;
        fx = fmaf(w0, f0.x, fx); fy = fmaf(w0, f0.y, fy);
    }
    float inv = 1.0f / dsum;
    int c0 = 2 * lane, c1 = 2 * lane + 1;
    if (c0 < NC) out[(size_t)t * NC + c0] = fmaf(fx, inv, b2[c0]);
    if (c1 < NC) out[(size_t)t * NC + c1] = fmaf(fy, inv, b2[c1]);
}

// ---------------- host launcher ----------------

extern "C" void kernel_launch(void* const* d_in, const int* in_sizes, int n_in,
                              void* d_out, int out_size, void* d_ws, size_t ws_size,
                              hipStream_t stream) {
    const float* x   = (const float*)d_in[0];
    const int*   ei  = (const int*)d_in[1];
    const float* W1  = (const float*)d_in[2];
    const float* aS1 = (const float*)d_in[3];
    const float* aD1 = (const float*)d_in[4];
    const float* b1  = (const float*)d_in[5];
    const float* W2  = (const float*)d_in[6];
    const float* aS2 = (const float*)d_in[7];
    const float* aD2 = (const float*)d_in[8];
    const float* b2  = (const float*)d_in[9];
    float* out = (float*)d_out;

    const int N = in_sizes[0] / 128;   // 50000
    const int E = in_sizes[1] / 2;     // 800000
    const int NC2 = 121;

    size_t off = 0;
    auto alloc = [&](size_t bytes) {
        size_t o = off;
        off = (off + bytes + 255) & ~(size_t)255;
        return o;
    };
    char* ws = (char*)d_ws;
    int*      cnt  = (int*)(ws + alloc((size_t)N * 4));
    int*      fill = (int*)(ws + alloc((size_t)N * 4));
    int*      rp   = (int*)(ws + alloc((size_t)(N + 1) * 4));
    int*      csr  = (int*)(ws + alloc((size_t)E * 4));
    int*      bsum = (int*)(ws + alloc(64 * 4));
    float*    alS1 = (float*)(ws + alloc((size_t)N * 8 * 4));
    float*    alD1 = (float*)(ws + alloc((size_t)N * 8 * 4));
    float*    alS2 = (float*)(ws + alloc((size_t)N * 4));
    float*    alD2 = (float*)(ws + alloc((size_t)N * 4));
    unsigned* gm1  = (unsigned*)(ws + alloc(8 * 4));
    unsigned* gm2  = (unsigned*)(ws + alloc(4));
    __half*   h1h  = (__half*)(ws + alloc((size_t)N * 128 * 2));
    float*    h2   = (float*)(ws + alloc((size_t)N * 128 * 4));
    __half*   h3h  = h1h;  // h1h dead after agg1; reuse (same footprint)
    if (ws_size < off) return;

    const int* src = ei;
    const int* dst = ei + E;

    hipMemsetAsync(cnt, 0, (size_t)N * 4, stream);
    hipMemsetAsync(fill, 0, (size_t)N * 4, stream);
    hipMemsetAsync(gm1, 0, 8 * 4, stream);
    hipMemsetAsync(gm2, 0, 4, stream);

    int eb = (E + 255) / 256;
    int nb = (N + 1023) / 1024;  // <= 64
    hist_kernel<<<eb, 256, 0, stream>>>(dst, cnt, E);
    scan_reduce<<<nb, 256, 0, stream>>>(cnt, bsum, N);
    scan_bsum<<<1, 64, 0, stream>>>(bsum, nb);
    scan_write<<<nb, 256, 0, stream>>>(cnt, bsum, rp, N);
    scatter_kernel<<<eb, 256, 0, stream>>>(src, dst, rp, fill, csr, E);

    int gb = (N + 127) / 128;
    int ab = (N + 3) / 4;
    gemm_k128_h<128, 128><<<gb, 256, 0, stream>>>(x, W1, h1h, N);
    al1_kernel<<<(N * 8 + 255) / 256, 256, 0, stream>>>(h1h, aS1, aD1, alS1, alD1, N);
    gmax_kernel<8><<<128, 256, 0, stream>>>(alS1, gm1, N * 8);
    agg1_kernel<<<ab, 256, 0, stream>>>(h1h, alS1, alD1, b1, rp, csr, gm1, h2, N);

    gemm_k128_h<121, 128><<<gb, 256, 0, stream>>>(h2, W2, h3h, N);
    al2_kernel<<<ab, 256, 0, stream>>>(h3h, aS2, aD2, alS2, alD2, N, NC2);
    gmax_kernel<1><<<128, 256, 0, stream>>>(alS2, gm2, N);
    agg2_kernel<<<ab, 256, 0, stream>>>(h3h, alS2, alD2, b2, rp, csr, gm2, out, N, NC2);
}

// Round 7
// 255.182 us; speedup vs baseline: 1.6103x; 1.2056x over previous
//
#include <hip/hip_runtime.h>
#include <hip/hip_fp16.h>

#define NEG_SLOPE 0.2f

typedef __fp16 half8v __attribute__((ext_vector_type(8)));
typedef float f32x4 __attribute__((ext_vector_type(4)));

__device__ __forceinline__ float lrelu(float x) {
    return fmaxf(x, 0.0f) + NEG_SLOPE * fminf(x, 0.0f);
}

// monotonic float<->uint key for atomicMax on floats (any sign)
__device__ __forceinline__ unsigned fkey(float f) {
    unsigned u = __float_as_uint(f);
    return (u & 0x80000000u) ? ~u : (u | 0x80000000u);
}
__device__ __forceinline__ float funkey(unsigned k) {
    return __uint_as_float((k & 0x80000000u) ? (k & 0x7fffffffu) : ~k);
}

// ---------------- CSR construction ----------------

__global__ void hist_kernel(const int* __restrict__ dst, int* __restrict__ cnt, int E) {
    int e = blockIdx.x * 256 + threadIdx.x;
    if (e < E) atomicAdd(&cnt[dst[e]], 1);
}

__global__ __launch_bounds__(256) void scan_reduce(const int* __restrict__ cnt,
                                                   int* __restrict__ bsum, int n) {
    __shared__ int sm[256];
    int base = blockIdx.x * 1024 + threadIdx.x * 4;
    int s = 0;
#pragma unroll
    for (int j = 0; j < 4; ++j) {
        int i = base + j;
        if (i < n) s += cnt[i];
    }
    sm[threadIdx.x] = s;
    __syncthreads();
#pragma unroll
    for (int off = 128; off >= 1; off >>= 1) {
        if (threadIdx.x < off) sm[threadIdx.x] += sm[threadIdx.x + off];
        __syncthreads();
    }
    if (threadIdx.x == 0) bsum[blockIdx.x] = sm[0];
}

__global__ __launch_bounds__(64) void scan_bsum(int* __restrict__ bsum, int nb) {
    int v = (threadIdx.x < (unsigned)nb) ? bsum[threadIdx.x] : 0;
    int x = v;
#pragma unroll
    for (int off = 1; off < 64; off <<= 1) {
        int y = __shfl_up(x, off);
        if ((int)threadIdx.x >= off) x += y;
    }
    if (threadIdx.x < (unsigned)nb) bsum[threadIdx.x] = x - v;  // exclusive
}

__global__ __launch_bounds__(256) void scan_write(const int* __restrict__ cnt,
                                                  const int* __restrict__ bsum,
                                                  int* __restrict__ rp, int n) {
    __shared__ int sm[256];
    int base = blockIdx.x * 1024 + threadIdx.x * 4;
    int v[4];
    int s = 0;
#pragma unroll
    for (int j = 0; j < 4; ++j) {
        int i = base + j;
        v[j] = (i < n) ? cnt[i] : 0;
        s += v[j];
    }
    sm[threadIdx.x] = s;
    __syncthreads();
#pragma unroll
    for (int off = 1; off < 256; off <<= 1) {
        int y = (threadIdx.x >= off) ? sm[threadIdx.x - off] : 0;
        __syncthreads();
        sm[threadIdx.x] += y;
        __syncthreads();
    }
    int run = sm[threadIdx.x] - s + bsum[blockIdx.x];
#pragma unroll
    for (int j = 0; j < 4; ++j) {
        int i = base + j;
        if (i < n) {
            rp[i] = run;
            run += v[j];
            if (i == n - 1) rp[n] = run;
        }
    }
}

__global__ void scatter_kernel(const int* __restrict__ src, const int* __restrict__ dst,
                               const int* __restrict__ rp, int* __restrict__ fill,
                               int* __restrict__ csr, int E) {
    int e = blockIdx.x * 256 + threadIdx.x;
    if (e < E) {
        int d = dst[e];
        int pos = rp[d] + atomicAdd(&fill[d], 1);
        csr[pos] = src[e];
    }
}

// ---------------- global per-head max of alS ----------------

template <int H>
__global__ __launch_bounds__(256) void gmax_kernel(const float* __restrict__ a,
                                                   unsigned* __restrict__ gm, int total) {
    __shared__ unsigned sm[256];
    unsigned loc = 0;
    int stride = 256 * gridDim.x;
    for (int i = blockIdx.x * 256 + threadIdx.x; i < total; i += stride)
        loc = max(loc, fkey(a[i]));
    sm[threadIdx.x] = loc;
    __syncthreads();
    for (int off = 128; off >= H; off >>= 1) {
        if (threadIdx.x < off) sm[threadIdx.x] = max(sm[threadIdx.x], sm[threadIdx.x + off]);
        __syncthreads();
    }
    if (threadIdx.x < H) atomicMax(&gm[threadIdx.x], sm[threadIdx.x]);
}

// ---------------- fp32 -> fp16 conversion (8 elems / thread) ----------------

__global__ __launch_bounds__(256) void cvt_half_kernel(const float* __restrict__ in,
                                                       __half* __restrict__ out, int total8) {
    int i = blockIdx.x * 256 + threadIdx.x;
    if (i >= total8) return;
    const float4* ip = (const float4*)in + (size_t)i * 2;
    float4 a = ip[0], b = ip[1];
    union { float4 f4; __half2 h[4]; } u;
    u.h[0] = __floats2half2_rn(a.x, a.y);
    u.h[1] = __floats2half2_rn(a.z, a.w);
    u.h[2] = __floats2half2_rn(b.x, b.y);
    u.h[3] = __floats2half2_rn(b.z, b.w);
    *((float4*)out + i) = u.f4;
}

// ---------------- MFMA GEMM: C[M,128(half)] = A[M,128(half)] @ B[128,NC(f32)] ------
// 256 threads = 4 waves; block computes 64 rows x 128 cols. B staged transposed in
// LDS as fp16 (cols >= NC zero-padded). Uses v_mfma_f32_16x16x32_f16; correctness
// relies only on (i,j)=lane%16 and the verified C/D map (k-permutation invariant).

template <int NC>
__global__ __launch_bounds__(256) void gemm_mfma(const __half* __restrict__ A,
                                                 const float* __restrict__ B,
                                                 __half* __restrict__ C, int M) {
    __shared__ __half Bt[128][136];  // [col][k], +8 halfs pad: rows hit distinct bank groups

    {   // stage Bt: thread t -> col c = t&127, k-half kq = t>>7; coalesced B row reads
        int t = threadIdx.x;
        int c = t & 127;
        int kq = t >> 7;
#pragma unroll
        for (int ch = 0; ch < 8; ++ch) {
            int k0 = kq * 64 + ch * 8;
            half8v hv;
#pragma unroll
            for (int j = 0; j < 8; ++j) {
                float v = (c < NC) ? B[(size_t)(k0 + j) * NC + c] : 0.0f;
                hv[j] = (__fp16)v;
            }
            *(half8v*)&Bt[c][k0] = hv;
        }
    }
    __syncthreads();

    const int wid = threadIdx.x >> 6;
    const int lane = threadIdx.x & 63;
    const int li = lane & 15;
    const int lg = lane >> 4;  // k-group 0..3

    int row = blockIdx.x * 64 + wid * 16 + li;
    int rowc = min(row, M - 1);  // clamp; OOB rows masked at store
    const half8v* Ap = (const half8v*)(A + (size_t)rowc * 128);

    half8v a[4];
#pragma unroll
    for (int ks = 0; ks < 4; ++ks) a[ks] = Ap[ks * 4 + lg];  // A[row][ks*32 + 8*lg ..+7]

    f32x4 acc[8];
#pragma unroll
    for (int ct = 0; ct < 8; ++ct) acc[ct] = (f32x4)0.0f;

#pragma unroll
    for (int ks = 0; ks < 4; ++ks) {
#pragma unroll
        for (int ct = 0; ct < 8; ++ct) {
            half8v b = *(const half8v*)&Bt[ct * 16 + li][ks * 32 + 8 * lg];
            acc[ct] = __builtin_amdgcn_mfma_f32_16x16x32_f16(a[ks], b, acc[ct], 0, 0, 0);
        }
    }

    int orow = blockIdx.x * 64 + wid * 16 + 4 * lg;
#pragma unroll
    for (int ct = 0; ct < 8; ++ct) {
#pragma unroll
        for (int r = 0; r < 4; ++r) {
            int rr = orow + r;
            if (rr < M) C[(size_t)rr * 128 + ct * 16 + li] = __float2half(acc[ct][r]);
        }
    }
}

// ---------------- attention logit dot products ----------------

__global__ void al1_kernel(const __half* __restrict__ h1h, const float* __restrict__ as,
                           const float* __restrict__ ad, float* __restrict__ alS,
                           float* __restrict__ alD, int N) {
    int g = blockIdx.x * 256 + threadIdx.x;
    if (g >= N * 8) return;
    int r = g >> 3, h = g & 7;
    const __half2* hp = (const __half2*)(h1h + (size_t)r * 128 + h * 16);
    const float* sp = as + h * 16;
    const float* dp = ad + h * 16;
    float s = 0.f, d = 0.f;
#pragma unroll
    for (int q = 0; q < 8; ++q) {
        float2 v = __half22float2(hp[q]);
        s = fmaf(v.x, sp[2 * q], s);
        d = fmaf(v.x, dp[2 * q], d);
        s = fmaf(v.y, sp[2 * q + 1], s);
        d = fmaf(v.y, dp[2 * q + 1], d);
    }
    alS[g] = s;
    alD[g] = d;
}

// h3h row stride = 128 halfs
__global__ __launch_bounds__(256) void al2_kernel(const __half* __restrict__ h3h,
                                                  const float* __restrict__ as,
                                                  const float* __restrict__ ad,
                                                  float* __restrict__ alS,
                                                  float* __restrict__ alD, int N, int NC) {
    int lane = threadIdx.x & 63;
    int r = blockIdx.x * 4 + (threadIdx.x >> 6);
    if (r >= N) return;
    float s = 0.f, d = 0.f;
    for (int c = lane; c < NC; c += 64) {
        float v = __half2float(h3h[(size_t)r * 128 + c]);
        s = fmaf(v, as[c], s);
        d = fmaf(v, ad[c], d);
    }
#pragma unroll
    for (int off = 32; off; off >>= 1) {
        s += __shfl_down(s, off);
        d += __shfl_down(d, off);
    }
    if (lane == 0) { alS[r] = s; alD[r] = d; }
}

// ---------------- layer-1 aggregation: one wave per dst node, half2 lanes --------
// Writes h2 in fp16 (feeds gemm2 A operand directly).

__global__ __launch_bounds__(256) void agg1_kernel(
    const __half* __restrict__ h1h, const float* __restrict__ alS,
    const float* __restrict__ alD, const float* __restrict__ b1,
    const int* __restrict__ rp, const int* __restrict__ csr,
    const unsigned* __restrict__ gm, __half* __restrict__ h2h, int N) {
    int t = blockIdx.x * 4 + (threadIdx.x >> 6);
    if (t >= N) return;
    int lane = threadIdx.x & 63;
    int h = lane >> 3;

    float adh = alD[t * 8 + h];
    float mh = lrelu(funkey(gm[h]) + adh);
    int e0 = rp[t], e1 = rp[t + 1];

    float ex = __expf(lrelu(alS[t * 8 + h] + adh) - mh);  // self loop
    float dsum = ex;
    float2 hs = __half22float2(*(const __half2*)(h1h + (size_t)t * 128 + 2 * lane));
    float fx = ex * hs.x, fy = ex * hs.y;

    int e = e0;
    for (; e + 4 <= e1; e += 4) {
        int s0 = csr[e], s1 = csr[e + 1], s2 = csr[e + 2], s3 = csr[e + 3];
        float w0 = __expf(lrelu(alS[s0 * 8 + h] + adh) - mh);
        float w1 = __expf(lrelu(alS[s1 * 8 + h] + adh) - mh);
        float w2 = __expf(lrelu(alS[s2 * 8 + h] + adh) - mh);
        float w3 = __expf(lrelu(alS[s3 * 8 + h] + adh) - mh);
        float2 f0 = __half22float2(*(const __half2*)(h1h + (size_t)s0 * 128 + 2 * lane));
        float2 f1 = __half22float2(*(const __half2*)(h1h + (size_t)s1 * 128 + 2 * lane));
        float2 f2 = __half22float2(*(const __half2*)(h1h + (size_t)s2 * 128 + 2 * lane));
        float2 f3 = __half22float2(*(const __half2*)(h1h + (size_t)s3 * 128 + 2 * lane));
        dsum += (w0 + w1) + (w2 + w3);
        fx = fmaf(w0, f0.x, fx); fy = fmaf(w0, f0.y, fy);
        fx = fmaf(w1, f1.x, fx); fy = fmaf(w1, f1.y, fy);
        fx = fmaf(w2, f2.x, fx); fy = fmaf(w2, f2.y, fy);
        fx = fmaf(w3, f3.x, fx); fy = fmaf(w3, f3.y, fy);
    }
    for (; e < e1; ++e) {
        int s0 = csr[e];
        float w0 = __expf(lrelu(alS[s0 * 8 + h] + adh) - mh);
        float2 f0 = __half22float2(*(const __half2*)(h1h + (size_t)s0 * 128 + 2 * lane));
        dsum += w0;
        fx = fmaf(w0, f0.x, fx); fy = fmaf(w0, f0.y, fy);
    }
    float inv = 1.0f / dsum;
    float2 bb = *(const float2*)(b1 + 2 * lane);
    float ox = fmaxf(fmaf(fx, inv, bb.x), 0.0f);
    float oy = fmaxf(fmaf(fy, inv, bb.y), 0.0f);
    *(__half2*)(h2h + (size_t)t * 128 + 2 * lane) = __floats2half2_rn(ox, oy);
}

// ---------------- layer-2 aggregation: one wave per dst node, half2 lanes --------

__global__ __launch_bounds__(256) void agg2_kernel(
    const __half* __restrict__ h3h, const float* __restrict__ alS,
    const float* __restrict__ alD, const float* __restrict__ b2,
    const int* __restrict__ rp, const int* __restrict__ csr,
    const unsigned* __restrict__ gm, float* __restrict__ out, int N, int NC) {
    int t = blockIdx.x * 4 + (threadIdx.x >> 6);
    if (t >= N) return;
    int lane = threadIdx.x & 63;

    float adT = alD[t];
    float m = lrelu(funkey(gm[0]) + adT);
    int e0 = rp[t], e1 = rp[t + 1];

    float ex = __expf(lrelu(alS[t] + adT) - m);
    float dsum = ex;
    float2 hs = __half22float2(*(const __half2*)(h3h + (size_t)t * 128 + 2 * lane));
    float fx = ex * hs.x, fy = ex * hs.y;  // pad cols are 0

    int e = e0;
    for (; e + 4 <= e1; e += 4) {
        int s0 = csr[e], s1 = csr[e + 1], s2 = csr[e + 2], s3 = csr[e + 3];
        float w0 = __expf(lrelu(alS[s0] + adT) - m);
        float w1 = __expf(lrelu(alS[s1] + adT) - m);
        float w2 = __expf(lrelu(alS[s2] + adT) - m);
        float w3 = __expf(lrelu(alS[s3] + adT) - m);
        float2 f0 = __half22float2(*(const __half2*)(h3h + (size_t)s0 * 128 + 2 * lane));
        float2 f1 = __half22float2(*(const __half2*)(h3h + (size_t)s1 * 128 + 2 * lane));
        float2 f2 = __half22float2(*(const __half2*)(h3h + (size_t)s2 * 128 + 2 * lane));
        float2 f3 = __half22float2(*(const __half2*)(h3h + (size_t)s3 * 128 + 2 * lane));
        dsum += (w0 + w1) + (w2 + w3);
        fx = fmaf(w0, f0.x, fx); fy = fmaf(w0, f0.y, fy);
        fx = fmaf(w1, f1.x, fx); fy = fmaf(w1, f1.y, fy);
        fx = fmaf(w2, f2.x, fx); fy = fmaf(w2, f2.y, fy);
        fx = fmaf(w3, f3.x, fx); fy = fmaf(w3, f3.y, fy);
    }
    for (; e < e1; ++e) {
        int s0 = csr[e];
        float w0 = __expf(lrelu(alS[s0] + adT) - m);
        float2 f0 = __half22float2(*(const __half2*)(h3h + (size_t)s0 * 128 + 2 * lane));
        dsum += w0;
        fx = fmaf(w0, f0.x, fx); fy = fmaf(w0, f0.y, fy);
    }
    float inv = 1.0f / dsum;
    int c0 = 2 * lane, c1 = 2 * lane + 1;
    if (c0 < NC) out[(size_t)t * NC + c0] = fmaf(fx, inv, b2[c0]);
    if (c1 < NC) out[(size_t)t * NC + c1] = fmaf(fy, inv, b2[c1]);
}

// ---------------- host launcher ----------------

extern "C" void kernel_launch(void* const* d_in, const int* in_sizes, int n_in,
                              void* d_out, int out_size, void* d_ws, size_t ws_size,
                              hipStream_t stream) {
    const float* x   = (const float*)d_in[0];
    const int*   ei  = (const int*)d_in[1];
    const float* W1  = (const float*)d_in[2];
    const float* aS1 = (const float*)d_in[3];
    const float* aD1 = (const float*)d_in[4];
    const float* b1  = (const float*)d_in[5];
    const float* W2  = (const float*)d_in[6];
    const float* aS2 = (const float*)d_in[7];
    const float* aD2 = (const float*)d_in[8];
    const float* b2  = (const float*)d_in[9];
    float* out = (float*)d_out;

    const int N = in_sizes[0] / 128;   // 50000
    const int E = in_sizes[1] / 2;     // 800000
    const int NC2 = 121;

    size_t off = 0;
    auto alloc = [&](size_t bytes) {
        size_t o = off;
        off = (off + bytes + 255) & ~(size_t)255;
        return o;
    };
    char* ws = (char*)d_ws;
    int*      cnt  = (int*)(ws + alloc((size_t)N * 4));
    int*      fill = (int*)(ws + alloc((size_t)N * 4));
    int*      rp   = (int*)(ws + alloc((size_t)(N + 1) * 4));
    int*      csr  = (int*)(ws + alloc((size_t)E * 4));
    int*      bsum = (int*)(ws + alloc(64 * 4));
    float*    alS1 = (float*)(ws + alloc((size_t)N * 8 * 4));
    float*    alD1 = (float*)(ws + alloc((size_t)N * 8 * 4));
    float*    alS2 = (float*)(ws + alloc((size_t)N * 4));
    float*    alD2 = (float*)(ws + alloc((size_t)N * 4));
    unsigned* gm1  = (unsigned*)(ws + alloc(8 * 4));
    unsigned* gm2  = (unsigned*)(ws + alloc(4));
    __half*   xh   = (__half*)(ws + alloc((size_t)N * 128 * 2));
    __half*   h1h  = (__half*)(ws + alloc((size_t)N * 128 * 2));
    __half*   h2h  = (__half*)(ws + alloc((size_t)N * 128 * 2));
    __half*   h3h  = h1h;  // h1h dead after agg1; reuse (same footprint)
    if (ws_size < off) return;

    const int* src = ei;
    const int* dst = ei + E;

    hipMemsetAsync(cnt, 0, (size_t)N * 4, stream);
    hipMemsetAsync(fill, 0, (size_t)N * 4, stream);
    hipMemsetAsync(gm1, 0, 8 * 4, stream);
    hipMemsetAsync(gm2, 0, 4, stream);

    int eb = (E + 255) / 256;
    int nb = (N + 1023) / 1024;  // <= 64
    hist_kernel<<<eb, 256, 0, stream>>>(dst, cnt, E);
    scan_reduce<<<nb, 256, 0, stream>>>(cnt, bsum, N);
    scan_bsum<<<1, 64, 0, stream>>>(bsum, nb);
    scan_write<<<nb, 256, 0, stream>>>(cnt, bsum, rp, N);
    scatter_kernel<<<eb, 256, 0, stream>>>(src, dst, rp, fill, csr, E);

    int cvb = (N * 128 / 8 + 255) / 256;
    cvt_half_kernel<<<cvb, 256, 0, stream>>>(x, xh, N * 128 / 8);

    int gmb = (N + 63) / 64;   // 782 blocks
    int ab = (N + 3) / 4;
    gemm_mfma<128><<<gmb, 256, 0, stream>>>(xh, W1, h1h, N);
    al1_kernel<<<(N * 8 + 255) / 256, 256, 0, stream>>>(h1h, aS1, aD1, alS1, alD1, N);
    gmax_kernel<8><<<128, 256, 0, stream>>>(alS1, gm1, N * 8);
    agg1_kernel<<<ab, 256, 0, stream>>>(h1h, alS1, alD1, b1, rp, csr, gm1, h2h, N);

    gemm_mfma<121><<<gmb, 256, 0, stream>>>(h2h, W2, h3h, N);
    al2_kernel<<<ab, 256, 0, stream>>>(h3h, aS2, aD2, alS2, alD2, N, NC2);
    gmax_kernel<1><<<128, 256, 0, stream>>>(alS2, gm2, N);
    agg2_kernel<<<ab, 256, 0, stream>>>(h3h, alS2, alD2, b2, rp, csr, gm2, out, N, NC2);
}

// Round 8
// 237.293 us; speedup vs baseline: 1.7317x; 1.0754x over previous
//
#include <hip/hip_runtime.h>
#include <hip/hip_fp16.h>

#define NEG_SLOPE 0.2f

typedef __fp16 half8v __attribute__((ext_vector_type(8)));
typedef float f32x4 __attribute__((ext_vector_type(4)));

__device__ __forceinline__ float lrelu(float x) {
    return fmaxf(x, 0.0f) + NEG_SLOPE * fminf(x, 0.0f);
}

__device__ __forceinline__ unsigned fkey(float f) {
    unsigned u = __float_as_uint(f);
    return (u & 0x80000000u) ? ~u : (u | 0x80000000u);
}
__device__ __forceinline__ float funkey(unsigned k) {
    return __uint_as_float((k & 0x80000000u) ? (k & 0x7fffffffu) : ~k);
}

// ---------------- edge pack: kv = (dst<<16) | src  (both < 65536) ----------------

__global__ void pack_kernel(const int* __restrict__ src, const int* __restrict__ dst,
                            unsigned* __restrict__ kv, int E) {
    int e = blockIdx.x * 256 + threadIdx.x;
    if (e < E) kv[e] = ((unsigned)dst[e] << 16) | (unsigned)src[e];
}

// ---------------- generic 3-phase exclusive scan (n <= 65536) ----------------

__global__ __launch_bounds__(256) void scan_reduce(const int* __restrict__ cnt,
                                                   int* __restrict__ bsum, int n) {
    __shared__ int sm[256];
    int base = blockIdx.x * 1024 + threadIdx.x * 4;
    int s = 0;
#pragma unroll
    for (int j = 0; j < 4; ++j) {
        int i = base + j;
        if (i < n) s += cnt[i];
    }
    sm[threadIdx.x] = s;
    __syncthreads();
#pragma unroll
    for (int off = 128; off >= 1; off >>= 1) {
        if (threadIdx.x < off) sm[threadIdx.x] += sm[threadIdx.x + off];
        __syncthreads();
    }
    if (threadIdx.x == 0) bsum[blockIdx.x] = sm[0];
}

__global__ __launch_bounds__(64) void scan_bsum(int* __restrict__ bsum, int nb) {
    int v = (threadIdx.x < (unsigned)nb) ? bsum[threadIdx.x] : 0;
    int x = v;
#pragma unroll
    for (int off = 1; off < 64; off <<= 1) {
        int y = __shfl_up(x, off);
        if ((int)threadIdx.x >= off) x += y;
    }
    if (threadIdx.x < (unsigned)nb) bsum[threadIdx.x] = x - v;  // exclusive
}

__global__ __launch_bounds__(256) void scan_write(const int* __restrict__ cnt,
                                                  const int* __restrict__ bsum,
                                                  int* __restrict__ rp, int n) {
    __shared__ int sm[256];
    int base = blockIdx.x * 1024 + threadIdx.x * 4;
    int v[4];
    int s = 0;
#pragma unroll
    for (int j = 0; j < 4; ++j) {
        int i = base + j;
        v[j] = (i < n) ? cnt[i] : 0;
        s += v[j];
    }
    sm[threadIdx.x] = s;
    __syncthreads();
#pragma unroll
    for (int off = 1; off < 256; off <<= 1) {
        int y = (threadIdx.x >= off) ? sm[threadIdx.x - off] : 0;
        __syncthreads();
        sm[threadIdx.x] += y;
        __syncthreads();
    }
    int run = sm[threadIdx.x] - s + bsum[blockIdx.x];
#pragma unroll
    for (int j = 0; j < 4; ++j) {
        int i = base + j;
        if (i < n) {
            rp[i] = run;
            run += v[j];
            if (i == n - 1) rp[n] = run;
        }
    }
}

// ---------------- radix pass: per-block histogram (bin-major global layout) --------

template <int SH>
__global__ __launch_bounds__(256) void rhist_kernel(const unsigned* __restrict__ kv,
                                                    int* __restrict__ h, int E, int nblk) {
    __shared__ int lh[256];
    lh[threadIdx.x] = 0;
    __syncthreads();
    int base = blockIdx.x * 4096;
#pragma unroll
    for (int j = 0; j < 16; ++j) {
        int i = base + j * 256 + threadIdx.x;
        if (i < E) atomicAdd(&lh[(kv[i] >> SH) & 255], 1);
    }
    __syncthreads();
    h[threadIdx.x * nblk + blockIdx.x] = lh[threadIdx.x];
}

// ---------------- radix pass: stable block-local sort + coalesced scatter ----------

template <int SH>
__global__ __launch_bounds__(256) void rscat_kernel(const unsigned* __restrict__ in,
                                                    unsigned* __restrict__ outv,
                                                    const int* __restrict__ scanned,
                                                    int E, int nblk) {
    __shared__ unsigned items[4096];
    __shared__ unsigned sorted[4096];
    __shared__ int lh[256], lstart[256], rbase[256];
    __shared__ int wcnt[4][256];

    int tid = threadIdx.x, blk = blockIdx.x;
    int base = blk * 4096;
    int k = min(4096, E - base);
    lh[tid] = 0;
    rbase[tid] = 0;
#pragma unroll
    for (int j = 0; j < 16; ++j) {
        int idx = j * 256 + tid;
        items[idx] = (base + idx < E) ? in[base + idx] : 0u;
    }
    __syncthreads();
#pragma unroll
    for (int j = 0; j < 16; ++j) {
        int idx = j * 256 + tid;
        if (idx < k) atomicAdd(&lh[(items[idx] >> SH) & 255], 1);
    }
    __syncthreads();
    // exclusive scan of lh -> lstart
    int sv = lh[tid];
    lstart[tid] = sv;
    __syncthreads();
    for (int off = 1; off < 256; off <<= 1) {
        int y = (tid >= off) ? lstart[tid - off] : 0;
        __syncthreads();
        lstart[tid] += y;
        __syncthreads();
    }
    int excl = lstart[tid] - sv;
    __syncthreads();
    lstart[tid] = excl;
    __syncthreads();

    int lane = tid & 63, wave = tid >> 6;
    for (int it = 0; it < 16; ++it) {
        int idx = it * 256 + tid;
        unsigned v = items[idx];
        int d = (v >> SH) & 255;
        bool valid = idx < k;
        unsigned long long vm = __ballot(valid);
        unsigned long long m = vm;
#pragma unroll
        for (int b = 0; b < 8; ++b) {
            unsigned long long bb = __ballot((d >> b) & 1);
            m &= ((d >> b) & 1) ? bb : ~bb;
        }
        int lanerank = __popcll(m & ((1ull << lane) - 1ull));
        int wtot = __popcll(m);
        wcnt[0][tid] = 0; wcnt[1][tid] = 0; wcnt[2][tid] = 0; wcnt[3][tid] = 0;
        __syncthreads();
        if (valid && lanerank == 0) wcnt[wave][d] = wtot;
        __syncthreads();
        if (valid) {
            int cw = 0;
            for (int w = 0; w < wave; ++w) cw += wcnt[w][d];
            sorted[lstart[d] + rbase[d] + cw + lanerank] = v;
        }
        __syncthreads();
        rbase[tid] += wcnt[0][tid] + wcnt[1][tid] + wcnt[2][tid] + wcnt[3][tid];
        __syncthreads();
    }
#pragma unroll
    for (int j = 0; j < 16; ++j) {
        int i = j * 256 + tid;
        if (i < k) {
            unsigned v = sorted[i];
            int d = (v >> SH) & 255;
            outv[scanned[d * nblk + blk] + (i - lstart[d])] = v;
        }
    }
}

// ---------------- row pointers from sorted kv ----------------

__global__ void rp_kernel(const unsigned* __restrict__ kv, int* __restrict__ rp,
                          int E, int N) {
    int i = blockIdx.x * 256 + threadIdx.x;
    if (i >= E) return;
    int cur = (int)(kv[i] >> 16);
    int prev = (i == 0) ? -1 : (int)(kv[i - 1] >> 16);
    for (int t = prev + 1; t <= cur; ++t) rp[t] = i;
    if (i == E - 1)
        for (int t = cur + 1; t <= N; ++t) rp[t] = E;
}

// ---------------- global per-head max of alS ----------------

template <int H>
__global__ __launch_bounds__(256) void gmax_kernel(const float* __restrict__ a,
                                                   unsigned* __restrict__ gm, int total) {
    __shared__ unsigned sm[256];
    unsigned loc = 0;
    int stride = 256 * gridDim.x;
    for (int i = blockIdx.x * 256 + threadIdx.x; i < total; i += stride)
        loc = max(loc, fkey(a[i]));
    sm[threadIdx.x] = loc;
    __syncthreads();
    for (int off = 128; off >= H; off >>= 1) {
        if (threadIdx.x < off) sm[threadIdx.x] = max(sm[threadIdx.x], sm[threadIdx.x + off]);
        __syncthreads();
    }
    if (threadIdx.x < H) atomicMax(&gm[threadIdx.x], sm[threadIdx.x]);
}

// ---------------- fp32 -> fp16 conversion (8 elems / thread) ----------------

__global__ __launch_bounds__(256) void cvt_half_kernel(const float* __restrict__ in,
                                                       __half* __restrict__ out, int total8) {
    int i = blockIdx.x * 256 + threadIdx.x;
    if (i >= total8) return;
    const float4* ip = (const float4*)in + (size_t)i * 2;
    float4 a = ip[0], b = ip[1];
    union { float4 f4; __half2 h[4]; } u;
    u.h[0] = __floats2half2_rn(a.x, a.y);
    u.h[1] = __floats2half2_rn(a.z, a.w);
    u.h[2] = __floats2half2_rn(b.x, b.y);
    u.h[3] = __floats2half2_rn(b.z, b.w);
    *((float4*)out + i) = u.f4;
}

// ---------------- MFMA GEMM: C[M,128(half)] = A[M,128(half)] @ B[128,NC(f32)] ------

template <int NC>
__global__ __launch_bounds__(256) void gemm_mfma(const __half* __restrict__ A,
                                                 const float* __restrict__ B,
                                                 __half* __restrict__ C, int M) {
    __shared__ __half Bt[128][136];

    {
        int t = threadIdx.x;
        int c = t & 127;
        int kq = t >> 7;
#pragma unroll
        for (int ch = 0; ch < 8; ++ch) {
            int k0 = kq * 64 + ch * 8;
            half8v hv;
#pragma unroll
            for (int j = 0; j < 8; ++j) {
                float v = (c < NC) ? B[(size_t)(k0 + j) * NC + c] : 0.0f;
                hv[j] = (__fp16)v;
            }
            *(half8v*)&Bt[c][k0] = hv;
        }
    }
    __syncthreads();

    const int wid = threadIdx.x >> 6;
    const int lane = threadIdx.x & 63;
    const int li = lane & 15;
    const int lg = lane >> 4;

    int row = blockIdx.x * 64 + wid * 16 + li;
    int rowc = min(row, M - 1);
    const half8v* Ap = (const half8v*)(A + (size_t)rowc * 128);

    half8v a[4];
#pragma unroll
    for (int ks = 0; ks < 4; ++ks) a[ks] = Ap[ks * 4 + lg];

    f32x4 acc[8];
#pragma unroll
    for (int ct = 0; ct < 8; ++ct) acc[ct] = (f32x4)0.0f;

#pragma unroll
    for (int ks = 0; ks < 4; ++ks) {
#pragma unroll
        for (int ct = 0; ct < 8; ++ct) {
            half8v b = *(const half8v*)&Bt[ct * 16 + li][ks * 32 + 8 * lg];
            acc[ct] = __builtin_amdgcn_mfma_f32_16x16x32_f16(a[ks], b, acc[ct], 0, 0, 0);
        }
    }

    int orow = blockIdx.x * 64 + wid * 16 + 4 * lg;
#pragma unroll
    for (int ct = 0; ct < 8; ++ct) {
#pragma unroll
        for (int r = 0; r < 4; ++r) {
            int rr = orow + r;
            if (rr < M) C[(size_t)rr * 128 + ct * 16 + li] = __float2half(acc[ct][r]);
        }
    }
}

// ---------------- attention logit dot products ----------------

__global__ void al1_kernel(const __half* __restrict__ h1h, const float* __restrict__ as,
                           const float* __restrict__ ad, float* __restrict__ alS,
                           float* __restrict__ alD, int N) {
    int g = blockIdx.x * 256 + threadIdx.x;
    if (g >= N * 8) return;
    int r = g >> 3, h = g & 7;
    const __half2* hp = (const __half2*)(h1h + (size_t)r * 128 + h * 16);
    const float* sp = as + h * 16;
    const float* dp = ad + h * 16;
    float s = 0.f, d = 0.f;
#pragma unroll
    for (int q = 0; q < 8; ++q) {
        float2 v = __half22float2(hp[q]);
        s = fmaf(v.x, sp[2 * q], s);
        d = fmaf(v.x, dp[2 * q], d);
        s = fmaf(v.y, sp[2 * q + 1], s);
        d = fmaf(v.y, dp[2 * q + 1], d);
    }
    alS[g] = s;
    alD[g] = d;
}

__global__ __launch_bounds__(256) void al2_kernel(const __half* __restrict__ h3h,
                                                  const float* __restrict__ as,
                                                  const float* __restrict__ ad,
                                                  float* __restrict__ alS,
                                                  float* __restrict__ alD, int N, int NC) {
    int lane = threadIdx.x & 63;
    int r = blockIdx.x * 4 + (threadIdx.x >> 6);
    if (r >= N) return;
    float s = 0.f, d = 0.f;
    for (int c = lane; c < NC; c += 64) {
        float v = __half2float(h3h[(size_t)r * 128 + c]);
        s = fmaf(v, as[c], s);
        d = fmaf(v, ad[c], d);
    }
#pragma unroll
    for (int off = 32; off; off >>= 1) {
        s += __shfl_down(s, off);
        d += __shfl_down(d, off);
    }
    if (lane == 0) { alS[r] = s; alD[r] = d; }
}

// ---------------- layer-1 aggregation: one wave per dst node, half2 lanes --------

__global__ __launch_bounds__(256) void agg1_kernel(
    const __half* __restrict__ h1h, const float* __restrict__ alS,
    const float* __restrict__ alD, const float* __restrict__ b1,
    const int* __restrict__ rp, const unsigned* __restrict__ kv,
    const unsigned* __restrict__ gm, __half* __restrict__ h2h, int N) {
    int t = blockIdx.x * 4 + (threadIdx.x >> 6);
    if (t >= N) return;
    int lane = threadIdx.x & 63;
    int h = lane >> 3;

    float adh = alD[t * 8 + h];
    float mh = lrelu(funkey(gm[h]) + adh);
    int e0 = rp[t], e1 = rp[t + 1];

    float ex = __expf(lrelu(alS[t * 8 + h] + adh) - mh);  // self loop
    float dsum = ex;
    float2 hs = __half22float2(*(const __half2*)(h1h + (size_t)t * 128 + 2 * lane));
    float fx = ex * hs.x, fy = ex * hs.y;

    int e = e0;
    for (; e + 4 <= e1; e += 4) {
        int s0 = (int)(kv[e] & 0xFFFFu), s1 = (int)(kv[e + 1] & 0xFFFFu);
        int s2 = (int)(kv[e + 2] & 0xFFFFu), s3 = (int)(kv[e + 3] & 0xFFFFu);
        float w0 = __expf(lrelu(alS[s0 * 8 + h] + adh) - mh);
        float w1 = __expf(lrelu(alS[s1 * 8 + h] + adh) - mh);
        float w2 = __expf(lrelu(alS[s2 * 8 + h] + adh) - mh);
        float w3 = __expf(lrelu(alS[s3 * 8 + h] + adh) - mh);
        float2 f0 = __half22float2(*(const __half2*)(h1h + (size_t)s0 * 128 + 2 * lane));
        float2 f1 = __half22float2(*(const __half2*)(h1h + (size_t)s1 * 128 + 2 * lane));
        float2 f2 = __half22float2(*(const __half2*)(h1h + (size_t)s2 * 128 + 2 * lane));
        float2 f3 = __half22float2(*(const __half2*)(h1h + (size_t)s3 * 128 + 2 * lane));
        dsum += (w0 + w1) + (w2 + w3);
        fx = fmaf(w0, f0.x, fx); fy = fmaf(w0, f0.y, fy);
        fx = fmaf(w1, f1.x, fx); fy = fmaf(w1, f1.y, fy);
        fx = fmaf(w2, f2.x, fx); fy = fmaf(w2, f2.y, fy);
        fx = fmaf(w3, f3.x, fx); fy = fmaf(w3, f3.y, fy);
    }
    for (; e < e1; ++e) {
        int s0 = (int)(kv[e] & 0xFFFFu);
        float w0 = __expf(lrelu(alS[s0 * 8 + h] + adh) - mh);
        float2 f0 = __half22float2(*(const __half2*)(h1h + (size_t)s0 * 128 + 2 * lane));
        dsum += w0;
        fx = fmaf(w0, f0.x, fx); fy = fmaf(w0, f0.y, fy);
    }
    float inv = 1.0f / dsum;
    float2 bb = *(const float2*)(b1 + 2 * lane);
    float ox = fmaxf(fmaf(fx, inv, bb.x), 0.0f);
    float oy = fmaxf(fmaf(fy, inv, bb.y), 0.0f);
    *(__half2*)(h2h + (size_t)t * 128 + 2 * lane) = __floats2half2_rn(ox, oy);
}

// ---------------- layer-2 aggregation: one wave per dst node, half2 lanes --------

__global__ __launch_bounds__(256) void agg2_kernel(
    const __half* __restrict__ h3h, const float* __restrict__ alS,
    const float* __restrict__ alD, const float* __restrict__ b2,
    const int* __restrict__ rp, const unsigned* __restrict__ kv,
    const unsigned* __restrict__ gm, float* __restrict__ out, int N, int NC) {
    int t = blockIdx.x * 4 + (threadIdx.x >> 6);
    if (t >= N) return;
    int lane = threadIdx.x & 63;

    float adT = alD[t];
    float m = lrelu(funkey(gm[0]) + adT);
    int e0 = rp[t], e1 = rp[t + 1];

    float ex = __expf(lrelu(alS[t] + adT) - m);
    float dsum = ex;
    float2 hs = __half22float2(*(const __half2*)(h3h + (size_t)t * 128 + 2 * lane));
    float fx = ex * hs.x, fy = ex * hs.y;  // pad cols are 0

    int e = e0;
    for (; e + 4 <= e1; e += 4) {
        int s0 = (int)(kv[e] & 0xFFFFu), s1 = (int)(kv[e + 1] & 0xFFFFu);
        int s2 = (int)(kv[e + 2] & 0xFFFFu), s3 = (int)(kv[e + 3] & 0xFFFFu);
        float w0 = __expf(lrelu(alS[s0] + adT) - m);
        float w1 = __expf(lrelu(alS[s1] + adT) - m);
        float w2 = __expf(lrelu(alS[s2] + adT) - m);
        float w3 = __expf(lrelu(alS[s3] + adT) - m);
        float2 f0 = __half22float2(*(const __half2*)(h3h + (size_t)s0 * 128 + 2 * lane));
        float2 f1 = __half22float2(*(const __half2*)(h3h + (size_t)s1 * 128 + 2 * lane));
        float2 f2 = __half22float2(*(const __half2*)(h3h + (size_t)s2 * 128 + 2 * lane));
        float2 f3 = __half22float2(*(const __half2*)(h3h + (size_t)s3 * 128 + 2 * lane));
        dsum += (w0 + w1) + (w2 + w3);
        fx = fmaf(w0, f0.x, fx); fy = fmaf(w0, f0.y, fy);
        fx = fmaf(w1, f1.x, fx); fy = fmaf(w1, f1.y, fy);
        fx = fmaf(w2, f2.x, fx); fy = fmaf(w2, f2.y, fy);
        fx = fmaf(w3, f3.x, fx); fy = fmaf(w3, f3.y, fy);
    }
    for (; e < e1; ++e) {
        int s0 = (int)(kv[e] & 0xFFFFu);
        float w0 = __expf(lrelu(alS[s0] + adT) - m);
        float2 f0 = __half22float2(*(const __half2*)(h3h + (size_t)s0 * 128 + 2 * lane));
        dsum += w0;
        fx = fmaf(w0, f0.x, fx); fy = fmaf(w0, f0.y, fy);
    }
    float inv = 1.0f / dsum;
    int c0 = 2 * lane, c1 = 2 * lane + 1;
    if (c0 < NC) out[(size_t)t * NC + c0] = fmaf(fx, inv, b2[c0]);
    if (c1 < NC) out[(size_t)t * NC + c1] = fmaf(fy, inv, b2[c1]);
}

// ---------------- host launcher ----------------

extern "C" void kernel_launch(void* const* d_in, const int* in_sizes, int n_in,
                              void* d_out, int out_size, void* d_ws, size_t ws_size,
                              hipStream_t stream) {
    const float* x   = (const float*)d_in[0];
    const int*   ei  = (const int*)d_in[1];
    const float* W1  = (const float*)d_in[2];
    const float* aS1 = (const float*)d_in[3];
    const float* aD1 = (const float*)d_in[4];
    const float* b1  = (const float*)d_in[5];
    const float* W2  = (const float*)d_in[6];
    const float* aS2 = (const float*)d_in[7];
    const float* aD2 = (const float*)d_in[8];
    const float* b2  = (const float*)d_in[9];
    float* out = (float*)d_out;

    const int N = in_sizes[0] / 128;   // 50000
    const int E = in_sizes[1] / 2;     // 800000
    const int NC2 = 121;

    const int NBLK = (E + 4095) / 4096;        // 196
    const int HN = 256 * NBLK;                 // 50176

    size_t off = 0;
    auto alloc = [&](size_t bytes) {
        size_t o = off;
        off = (off + bytes + 255) & ~(size_t)255;
        return o;
    };
    char* ws = (char*)d_ws;
    unsigned* kv0  = (unsigned*)(ws + alloc((size_t)E * 4));
    unsigned* kv1  = (unsigned*)(ws + alloc((size_t)E * 4));
    int*      h    = (int*)(ws + alloc((size_t)(HN + 1) * 4));
    int*      hs   = (int*)(ws + alloc((size_t)(HN + 1) * 4));
    int*      rp   = (int*)(ws + alloc((size_t)(N + 1) * 4));
    int*      bsum = (int*)(ws + alloc(64 * 4));
    float*    alS1 = (float*)(ws + alloc((size_t)N * 8 * 4));
    float*    alD1 = (float*)(ws + alloc((size_t)N * 8 * 4));
    float*    alS2 = (float*)(ws + alloc((size_t)N * 4));
    float*    alD2 = (float*)(ws + alloc((size_t)N * 4));
    unsigned* gm1  = (unsigned*)(ws + alloc(8 * 4));
    unsigned* gm2  = (unsigned*)(ws + alloc(4));
    __half*   xh   = (__half*)(ws + alloc((size_t)N * 128 * 2));
    __half*   h1h  = (__half*)(ws + alloc((size_t)N * 128 * 2));
    __half*   h2h  = (__half*)(ws + alloc((size_t)N * 128 * 2));
    __half*   h3h  = h1h;  // h1h dead after agg1; reuse
    if (ws_size < off) return;

    const int* src = ei;
    const int* dst = ei + E;

    hipMemsetAsync(gm1, 0, 8 * 4, stream);
    hipMemsetAsync(gm2, 0, 4, stream);

    int eb = (E + 255) / 256;
    int snb = (HN + 1023) / 1024;  // 49 <= 64

    // radix sort by dst (bytes 2 then 3), CSR = sorted kv
    pack_kernel<<<eb, 256, 0, stream>>>(src, dst, kv0, E);
    rhist_kernel<16><<<NBLK, 256, 0, stream>>>(kv0, h, E, NBLK);
    scan_reduce<<<snb, 256, 0, stream>>>(h, bsum, HN);
    scan_bsum<<<1, 64, 0, stream>>>(bsum, snb);
    scan_write<<<snb, 256, 0, stream>>>(h, bsum, hs, HN);
    rscat_kernel<16><<<NBLK, 256, 0, stream>>>(kv0, kv1, hs, E, NBLK);
    rhist_kernel<24><<<NBLK, 256, 0, stream>>>(kv1, h, E, NBLK);
    scan_reduce<<<snb, 256, 0, stream>>>(h, bsum, HN);
    scan_bsum<<<1, 64, 0, stream>>>(bsum, snb);
    scan_write<<<snb, 256, 0, stream>>>(h, bsum, hs, HN);
    rscat_kernel<24><<<NBLK, 256, 0, stream>>>(kv1, kv0, hs, E, NBLK);
    rp_kernel<<<eb, 256, 0, stream>>>(kv0, rp, E, N);

    int cvb = (N * 128 / 8 + 255) / 256;
    cvt_half_kernel<<<cvb, 256, 0, stream>>>(x, xh, N * 128 / 8);

    int gmb = (N + 63) / 64;
    int ab = (N + 3) / 4;
    gemm_mfma<128><<<gmb, 256, 0, stream>>>(xh, W1, h1h, N);
    al1_kernel<<<(N * 8 + 255) / 256, 256, 0, stream>>>(h1h, aS1, aD1, alS1, alD1, N);
    gmax_kernel<8><<<128, 256, 0, stream>>>(alS1, gm1, N * 8);
    agg1_kernel<<<ab, 256, 0, stream>>>(h1h, alS1, alD1, b1, rp, kv0, gm1, h2h, N);

    gemm_mfma<121><<<gmb, 256, 0, stream>>>(h2h, W2, h3h, N);
    al2_kernel<<<ab, 256, 0, stream>>>(h3h, aS2, aD2, alS2, alD2, N, NC2);
    gmax_kernel<1><<<128, 256, 0, stream>>>(alS2, gm2, N);
    agg2_kernel<<<ab, 256, 0, stream>>>(h3h, alS2, alD2, b2, rp, kv0, gm2, out, N, NC2);
}